// Round 6
// baseline (1144.012 us; speedup 1.0000x reference)
//
#include <hip/hip_runtime.h>
#include <math.h>

#define NT_NODES 30000
#define NE_EDGES 200000
#define NTY 3
#define NRL 4
#define NLY 2
#define NH 8
#define HD 16
#define FDIM 128
#define SCAN_BLOCKS 118   // ceil(30000/256)

typedef unsigned short u16;
typedef unsigned int u32;

__device__ __forceinline__ float bf2f(u16 u) {
  return __uint_as_float(((u32)u) << 16);
}
__device__ __forceinline__ u16 f2bf(float f) {   // RNE
  u32 u = __float_as_uint(f);
  return (u16)((u + 0x7FFFu + ((u >> 16) & 1u)) >> 16);
}

// ---------------------------------------------------------------- GEMM ------
struct GemmTask {
  const float* A; const float* W; const float* bias; float* C;
  const float* oldh; const float* skipp;
};
struct GemmBatch { GemmTask t[7]; };

__device__ __forceinline__ float gelu_f(float x) {
  return 0.5f * x * (1.f + erff(x * 0.7071067811865475f));
}

// C[M,128] = epi(preA(A)[M,128] @ W[128,128] + bias)
template<int GELU_A, int EPI_SKIP, int RELU, int BF16_OUT>
__global__ __launch_bounds__(256) void gemm_f32(GemmBatch gb, int M) {
  const GemmTask tk = gb.t[blockIdx.z];
  const int tid = threadIdx.x;
  const int tx2 = tid & 15;    // col group of 8
  const int ty2 = tid >> 4;    // row group of 4
  const int row0 = blockIdx.x * 64;

  __shared__ float AsT[32][64];   // transposed A chunk [k][row]
  __shared__ float Bs[32][128];   // B chunk [k][col]

  float acc[4][8];
  #pragma unroll
  for (int i = 0; i < 4; i++)
    #pragma unroll
    for (int j = 0; j < 8; j++) acc[i][j] = 0.f;

  for (int k0 = 0; k0 < FDIM; k0 += 32) {
    #pragma unroll
    for (int i = 0; i < 2; i++) {
      int slot = tid + 256 * i;         // 0..511
      int r = slot >> 3, f4 = slot & 7;
      int grow = row0 + r;
      float4 v = make_float4(0.f, 0.f, 0.f, 0.f);
      if (grow < M) v = *(const float4*)(tk.A + (size_t)grow * FDIM + k0 + f4 * 4);
      if (GELU_A) { v.x = gelu_f(v.x); v.y = gelu_f(v.y); v.z = gelu_f(v.z); v.w = gelu_f(v.w); }
      AsT[f4 * 4 + 0][r] = v.x;
      AsT[f4 * 4 + 1][r] = v.y;
      AsT[f4 * 4 + 2][r] = v.z;
      AsT[f4 * 4 + 3][r] = v.w;
    }
    #pragma unroll
    for (int i = 0; i < 4; i++) {
      int slot = tid + 256 * i;         // 0..1023
      int r = slot >> 5, f4 = slot & 31;
      float4 v = *(const float4*)(tk.W + (size_t)(k0 + r) * FDIM + f4 * 4);
      *(float4*)(&Bs[r][f4 * 4]) = v;
    }
    __syncthreads();
    #pragma unroll
    for (int kk = 0; kk < 32; kk++) {
      float4 a4 = *(const float4*)(&AsT[kk][ty2 * 4]);
      float4 b0 = *(const float4*)(&Bs[kk][tx2 * 8]);
      float4 b1 = *(const float4*)(&Bs[kk][tx2 * 8 + 4]);
      const float av[4] = {a4.x, a4.y, a4.z, a4.w};
      #pragma unroll
      for (int i = 0; i < 4; i++) {
        acc[i][0] += av[i] * b0.x; acc[i][1] += av[i] * b0.y;
        acc[i][2] += av[i] * b0.z; acc[i][3] += av[i] * b0.w;
        acc[i][4] += av[i] * b1.x; acc[i][5] += av[i] * b1.y;
        acc[i][6] += av[i] * b1.z; acc[i][7] += av[i] * b1.w;
      }
    }
    __syncthreads();
  }

  float4 bias0 = *(const float4*)(tk.bias + tx2 * 8);
  float4 bias1 = *(const float4*)(tk.bias + tx2 * 8 + 4);
  float a_s = 0.f;
  if (EPI_SKIP) a_s = 1.f / (1.f + expf(-tk.skipp[0]));

  #pragma unroll
  for (int i = 0; i < 4; i++) {
    int grow = row0 + ty2 * 4 + i;
    if (grow >= M) continue;
    float o[8];
    o[0] = acc[i][0] + bias0.x; o[1] = acc[i][1] + bias0.y;
    o[2] = acc[i][2] + bias0.z; o[3] = acc[i][3] + bias0.w;
    o[4] = acc[i][4] + bias1.x; o[5] = acc[i][5] + bias1.y;
    o[6] = acc[i][6] + bias1.z; o[7] = acc[i][7] + bias1.w;
    if (RELU) {
      #pragma unroll
      for (int j = 0; j < 8; j++) o[j] = fmaxf(o[j], 0.f);
    }
    if (EPI_SKIP) {
      const float* hp = tk.oldh + (size_t)grow * FDIM + tx2 * 8;
      float4 h0 = *(const float4*)(hp);
      float4 h1 = *(const float4*)(hp + 4);
      float b_s = 1.f - a_s;
      o[0] = a_s * o[0] + b_s * h0.x; o[1] = a_s * o[1] + b_s * h0.y;
      o[2] = a_s * o[2] + b_s * h0.z; o[3] = a_s * o[3] + b_s * h0.w;
      o[4] = a_s * o[4] + b_s * h1.x; o[5] = a_s * o[5] + b_s * h1.y;
      o[6] = a_s * o[6] + b_s * h1.z; o[7] = a_s * o[7] + b_s * h1.w;
    }
    if (BF16_OUT) {
      u32 p0 = (u32)f2bf(o[0]) | ((u32)f2bf(o[1]) << 16);
      u32 p1 = (u32)f2bf(o[2]) | ((u32)f2bf(o[3]) << 16);
      u32 p2 = (u32)f2bf(o[4]) | ((u32)f2bf(o[5]) << 16);
      u32 p3 = (u32)f2bf(o[6]) | ((u32)f2bf(o[7]) << 16);
      u16* cp = ((u16*)tk.C) + (size_t)grow * FDIM + tx2 * 8;
      *(uint4*)cp = make_uint4(p0, p1, p2, p3);
    } else {
      float* cp = tk.C + (size_t)grow * FDIM + tx2 * 8;
      *(float4*)cp = make_float4(o[0], o[1], o[2], o[3]);
      *(float4*)(cp + 4) = make_float4(o[4], o[5], o[6], o[7]);
    }
  }
}

// ------------------------------------------------------------- CSR build ----
__global__ __launch_bounds__(256) void csr_hist(const int* __restrict__ edge_index,
                                                int* __restrict__ counts) {
  int idx = blockIdx.x * 256 + threadIdx.x;
  if (idx >= NRL * NE_EDGES) return;
  int r = idx / NE_EDGES, e = idx - r * NE_EDGES;
  int d = edge_index[(size_t)(r * 2 + 1) * NE_EDGES + e];
  atomicAdd(&counts[r * NT_NODES + d], 1);
}

// hierarchical scan: block-local -> aux -> add-back
__global__ __launch_bounds__(256) void scan_block(const int* __restrict__ counts,
                                                  int* __restrict__ off,
                                                  int* __restrict__ aux) {
  int r = blockIdx.y, b = blockIdx.x, t = threadIdx.x;
  int i = b * 256 + t;
  int v = (i < NT_NODES) ? counts[r * NT_NODES + i] : 0;
  __shared__ int lds[256];
  lds[t] = v;
  __syncthreads();
  #pragma unroll
  for (int dlt = 1; dlt < 256; dlt <<= 1) {
    int x = (t >= dlt) ? lds[t - dlt] : 0;
    __syncthreads();
    lds[t] += x;
    __syncthreads();
  }
  if (i < NT_NODES) off[(size_t)r * (NT_NODES + 1) + i] = lds[t] - v;  // block-local exclusive
  if (t == 255) aux[r * SCAN_BLOCKS + b] = lds[255];
}

__global__ __launch_bounds__(128) void scan_aux(const int* __restrict__ aux,
                                                int* __restrict__ auxe,
                                                int* __restrict__ off) {
  int r = blockIdx.x, t = threadIdx.x;
  __shared__ int lds[128];
  int v = (t < SCAN_BLOCKS) ? aux[r * SCAN_BLOCKS + t] : 0;
  lds[t] = v;
  __syncthreads();
  #pragma unroll
  for (int dlt = 1; dlt < 128; dlt <<= 1) {
    int x = (t >= dlt) ? lds[t - dlt] : 0;
    __syncthreads();
    lds[t] += x;
    __syncthreads();
  }
  if (t < SCAN_BLOCKS) auxe[r * SCAN_BLOCKS + t] = lds[t] - v;   // exclusive
  if (t == 127) off[(size_t)r * (NT_NODES + 1) + NT_NODES] = lds[127];  // grand total
}

__global__ __launch_bounds__(256) void scan_add(const int* __restrict__ auxe,
                                                int* __restrict__ off,
                                                int* __restrict__ cursor) {
  int r = blockIdx.y, b = blockIdx.x, t = threadIdx.x;
  int i = b * 256 + t;
  if (i >= NT_NODES) return;
  int val = off[(size_t)r * (NT_NODES + 1) + i] + auxe[r * SCAN_BLOCKS + b];
  off[(size_t)r * (NT_NODES + 1) + i] = val;
  cursor[r * NT_NODES + i] = val;
}

__global__ __launch_bounds__(256) void csr_scatter(const int* __restrict__ edge_index,
                                                   int* __restrict__ cursor,
                                                   int* __restrict__ csr_src) {
  int idx = blockIdx.x * 256 + threadIdx.x;
  if (idx >= NRL * NE_EDGES) return;
  int r = idx / NE_EDGES, e = idx - r * NE_EDGES;
  int s = edge_index[(size_t)(r * 2 + 0) * NE_EDGES + e];
  int d = edge_index[(size_t)(r * 2 + 1) * NE_EDGES + e];
  int pos = atomicAdd(&cursor[r * NT_NODES + d], 1);
  csr_src[(size_t)r * NE_EDGES + pos] = s;
}

// ---------------------------------------------------- fused attention -------
// One wave per dst node; TWO edges in flight per iteration (half-wave each).
// Lane layout: half = lane>>5 (edge slot), ln = lane&31 owns channels
// 4ln..4ln+3 (ushort4, 8B). Head h = ln>>2 (4 lanes); dot-reduce = 2 shfl_xor.
// Final cross-half combine via shfl_xor(…,32). 1 K-request + 1 V-request per
// 2 edges -> 2x MLP and half the instructions vs round-5 layout.
struct AttnRel {
  const int* csr_src; const int* off;
  const u16* q;        // bf16 Q of dst type [N,128]
  const u16* kraw;     // bf16 raw K of src type [N,128]
  const u16* vraw;     // bf16 raw V of src type [N,128]
  const float* Arel;   // [8][16][16]
  const float* Mrel;   // [8][16][16]
  const float* prel;   // [8]
  float* agg;          // agg of dst type [N,128]
  int accum;
};
struct AttnBatch { AttnRel r[3]; };

__global__ __launch_bounds__(256) void attn_fused(AttnBatch ab) {
  const AttnRel rp = ab.r[blockIdx.y];
  const int wave = threadIdx.x >> 6;
  const int lane = threadIdx.x & 63;
  const int d = blockIdx.x * 4 + wave;
  if (d >= NT_NODES) return;
  const int half = lane >> 5;
  const int ln = lane & 31;        // channel-quad index (channels 4ln..4ln+3)
  const int h = ln >> 2;           // head 0..7
  const int cl0 = (ln & 3) * 4;    // local channel base within head
  const int gbase = lane & ~3;     // first lane of 4-lane head group (same half)

  // ---- q' = (A_h @ q_h) * p_h/4, distributed over 4-lane head groups ----
  ushort4 qu = ((const ushort4*)rp.q)[(size_t)d * 32 + ln];
  float qf[4] = {bf2f(qu.x), bf2f(qu.y), bf2f(qu.z), bf2f(qu.w)};
  const float* A = rp.Arel + (size_t)h * 256;
  float qp[4] = {0.f, 0.f, 0.f, 0.f};
  #pragma unroll
  for (int g = 0; g < 4; g++) {
    #pragma unroll
    for (int j2 = 0; j2 < 4; j2++) {
      float qe = __shfl(qf[j2], gbase + g, 64);    // q element e = g*4+j2
      int e = g * 4 + j2;
      #pragma unroll
      for (int j = 0; j < 4; j++)
        qp[j] += A[(cl0 + j) * 16 + e] * qe;
    }
  }
  float scp = rp.prel[h] * 0.25f;
  #pragma unroll
  for (int j = 0; j < 4; j++) qp[j] *= scp;

  // ---- edge loop: 2 edges per iteration (one per half-wave) ----
  int lo = rp.off[d], hi = rp.off[d + 1];
  float acc[4] = {0.f, 0.f, 0.f, 0.f};
  float ssum = 0.f;
  #pragma unroll 2
  for (int pb = lo; pb < hi; pb += 2) {
    int pe = pb + half;
    int valid = (pe < hi);
    int s = rp.csr_src[valid ? pe : pb];
    ushort4 ku = ((const ushort4*)rp.kraw)[(size_t)s * 32 + ln];
    ushort4 vu = ((const ushort4*)rp.vraw)[(size_t)s * 32 + ln];
    float pd = qp[0] * bf2f(ku.x) + qp[1] * bf2f(ku.y)
             + qp[2] * bf2f(ku.z) + qp[3] * bf2f(ku.w);
    pd += __shfl_xor(pd, 1, 64);
    pd += __shfl_xor(pd, 2, 64);
    float ev = valid ? __expf(pd) : 0.f;
    acc[0] += ev * bf2f(vu.x); acc[1] += ev * bf2f(vu.y);
    acc[2] += ev * bf2f(vu.z); acc[3] += ev * bf2f(vu.w);
    ssum += ev;
  }
  // combine halves
  ssum += __shfl_xor(ssum, 32, 64);
  #pragma unroll
  for (int j = 0; j < 4; j++) acc[j] += __shfl_xor(acc[j], 32, 64);
  float inv = 1.f / (ssum + 1e-16f);
  float S[4] = {acc[0] * inv, acc[1] * inv, acc[2] * inv, acc[3] * inv};

  // ---- apply M_rel: out_cl = sum_{d2} S[d2] * M[h][d2][cl] ----
  const float* M = rp.Mrel + (size_t)h * 256;
  float o[4] = {0.f, 0.f, 0.f, 0.f};
  #pragma unroll
  for (int g = 0; g < 4; g++) {
    #pragma unroll
    for (int j2 = 0; j2 < 4; j2++) {
      float sv = __shfl(S[j2], gbase + g, 64);    // S_{d2 = g*4+j2}
      int d2 = g * 4 + j2;
      #pragma unroll
      for (int j = 0; j < 4; j++)
        o[j] += sv * M[d2 * 16 + cl0 + j];
    }
  }
  if (half == 0) {
    float* ap = rp.agg + (size_t)d * FDIM + 4 * ln;
    if (rp.accum) {
      float4 old = *(float4*)ap;
      *(float4*)ap = make_float4(old.x + o[0], old.y + o[1], old.z + o[2], old.w + o[3]);
    } else {
      *(float4*)ap = make_float4(o[0], o[1], o[2], o[3]);
    }
  }
}

// ---------------------------------------------------------------- scatter ---
__global__ __launch_bounds__(256) void scatter_out(const float* h0, const float* h1,
                                                   const float* h2, const int* ntype,
                                                   float* out, int NN) {
  int idx = blockIdx.x * 256 + threadIdx.x;
  if (idx >= NN * 32) return;
  int i = idx >> 5, c4 = idx & 31;
  int t = ntype[i];
  const float* hp = (t == 0) ? h0 : ((t == 1) ? h1 : h2);
  int local = i - t * NT_NODES;   // node_type_argmax is contiguous blocks per type
  ((float4*)out)[idx] = ((const float4*)hp)[(size_t)local * 32 + c4];
}

// ------------------------------------------------------------------- host ---
static const int ESRC[NRL] = {0, 0, 1, 0};
static const int EDST[NRL] = {0, 1, 0, 2};

extern "C" void kernel_launch(void* const* d_in, const int* in_sizes, int n_in,
                              void* d_out, int out_size, void* d_ws, size_t ws_size,
                              hipStream_t stream) {
  const float* x[3] = {(const float*)d_in[0], (const float*)d_in[1], (const float*)d_in[2]};
  const float* lin_w = (const float*)d_in[4];
  const float* lin_b = (const float*)d_in[5];
  const float* k_w   = (const float*)d_in[6];
  const float* k_b   = (const float*)d_in[7];
  const float* q_w   = (const float*)d_in[8];
  const float* q_b   = (const float*)d_in[9];
  const float* v_w   = (const float*)d_in[10];
  const float* v_b   = (const float*)d_in[11];
  const float* a_w   = (const float*)d_in[12];
  const float* a_b   = (const float*)d_in[13];
  const float* skip  = (const float*)d_in[14];
  const float* a_rel = (const float*)d_in[15];
  const float* m_rel = (const float*)d_in[16];
  const float* p_rel = (const float*)d_in[17];
  const int* edge_index = (const int*)d_in[18];
  const int* ntype   = (const int*)d_in[19];
  float* out = (float*)d_out;

  const size_t NF = (size_t)NT_NODES * FDIM;   // 3.84M elems per [N,128]
  float* p = (float*)d_ws;
  auto alloc = [&](size_t n) { float* r = p; p += n; return r; };
  float* bufA = alloc(3 * NF);                    // h (ping)
  float* bufB = alloc(3 * NF);                    // h (pong); bf16 Q aliases alt
  float* agg  = alloc(3 * NF);                    // edge aggregation (raw-V space)
  u16* kbf0 = (u16*)alloc(NF / 2);                // bf16 K, src type 0
  u16* vbf0 = (u16*)alloc(NF / 2);                // bf16 V, src type 0
  u16* kbf1 = (u16*)alloc(NF / 2);                // bf16 K, src type 1
  u16* vbf1 = (u16*)alloc(NF / 2);                // bf16 V, src type 1
  int* counts  = (int*)(p);                       // [4][N]
  int* cursor  = counts + NRL * NT_NODES;         // [4][N]
  int* offsets = cursor + NRL * NT_NODES;         // [4][N+1]
  int* aux     = offsets + NRL * (NT_NODES + 1);  // [4][118]
  int* auxe    = aux + NRL * SCAN_BLOCKS;         // [4][118]
  int* csr_src = auxe + NRL * SCAN_BLOCKS;        // [4][E]

  const int gemm_gx = (NT_NODES + 63) / 64;   // 469

  // ---- CSR build (edge_index fixed within a call; reused by both layers) ----
  hipMemsetAsync(counts, 0, NRL * NT_NODES * sizeof(int), stream);
  csr_hist<<<dim3((NRL * NE_EDGES + 255) / 256), 256, 0, stream>>>(edge_index, counts);
  scan_block<<<dim3(SCAN_BLOCKS, NRL), 256, 0, stream>>>(counts, offsets, aux);
  scan_aux<<<dim3(NRL), 128, 0, stream>>>(aux, auxe, offsets);
  scan_add<<<dim3(SCAN_BLOCKS, NRL), 256, 0, stream>>>(auxe, offsets, cursor);
  csr_scatter<<<dim3((NRL * NE_EDGES + 255) / 256), 256, 0, stream>>>(edge_index, cursor, csr_src);

  // input projection: hs[t] = relu(x_t @ lin_w[t] + lin_b[t])
  {
    GemmBatch gb{};
    for (int t = 0; t < 3; t++) {
      gb.t[t].A = x[t];
      gb.t[t].W = lin_w + (size_t)t * FDIM * FDIM;
      gb.t[t].bias = lin_b + (size_t)t * FDIM;
      gb.t[t].C = bufA + (size_t)t * NF;
    }
    gemm_f32<0, 0, 1, 0><<<dim3(gemm_gx, 1, 3), 256, 0, stream>>>(gb, NT_NODES);
  }

  float* cur = bufA;   // current h (fp32)
  float* alt = bufB;   // bf16 Q scratch now, fp32 next-h later
  for (int l = 0; l < NLY; l++) {
    u16* qbf = (u16*)alt;

    // Q for all 3 types + raw K/V for src types 0 and 1 — all bf16, one launch
    {
      GemmBatch gb{};
      for (int t = 0; t < 3; t++) {
        gb.t[t].A = cur + (size_t)t * NF;
        gb.t[t].W = q_w + (size_t)(l * NTY + t) * FDIM * FDIM;
        gb.t[t].bias = q_b + (size_t)(l * NTY + t) * FDIM;
        gb.t[t].C = (float*)(qbf + (size_t)t * NF);
      }
      gb.t[3].A = cur;                                   // src type 0
      gb.t[3].W = k_w + (size_t)(l * NTY + 0) * FDIM * FDIM;
      gb.t[3].bias = k_b + (size_t)(l * NTY + 0) * FDIM;
      gb.t[3].C = (float*)kbf0;
      gb.t[4].A = cur;
      gb.t[4].W = v_w + (size_t)(l * NTY + 0) * FDIM * FDIM;
      gb.t[4].bias = v_b + (size_t)(l * NTY + 0) * FDIM;
      gb.t[4].C = (float*)vbf0;
      gb.t[5].A = cur + NF;                              // src type 1
      gb.t[5].W = k_w + (size_t)(l * NTY + 1) * FDIM * FDIM;
      gb.t[5].bias = k_b + (size_t)(l * NTY + 1) * FDIM;
      gb.t[5].C = (float*)kbf1;
      gb.t[6].A = cur + NF;
      gb.t[6].W = v_w + (size_t)(l * NTY + 1) * FDIM * FDIM;
      gb.t[6].bias = v_b + (size_t)(l * NTY + 1) * FDIM;
      gb.t[6].C = (float*)vbf1;
      gemm_f32<0, 0, 0, 1><<<dim3(gemm_gx, 1, 7), 256, 0, stream>>>(gb, NT_NODES);
    }

    // attention launch A: relations {0,1,3} (src type 0; dst types 0,1,2
    // disjoint -> agg overwritten, no memset needed)
    {
      AttnBatch ab{};
      const int rels[3] = {0, 1, 3};
      for (int j = 0; j < 3; j++) {
        int r = rels[j], dt = EDST[r];
        ab.r[j].csr_src = csr_src + (size_t)r * NE_EDGES;
        ab.r[j].off  = offsets + (size_t)r * (NT_NODES + 1);
        ab.r[j].q    = qbf + (size_t)dt * NF;
        ab.r[j].kraw = kbf0;
        ab.r[j].vraw = vbf0;
        ab.r[j].Arel = a_rel + (size_t)(l * NRL + r) * NH * HD * HD;
        ab.r[j].Mrel = m_rel + (size_t)(l * NRL + r) * NH * HD * HD;
        ab.r[j].prel = p_rel + (size_t)(l * NRL + r) * NH;
        ab.r[j].agg  = agg + (size_t)dt * NF;
        ab.r[j].accum = 0;
      }
      attn_fused<<<dim3((NT_NODES + 3) / 4, 3), 256, 0, stream>>>(ab);
    }

    // attention launch B: relation {2} (src type 1, dst type 0, accumulate)
    {
      AttnBatch ab{};
      int r = 2, dt = EDST[r];
      ab.r[0].csr_src = csr_src + (size_t)r * NE_EDGES;
      ab.r[0].off  = offsets + (size_t)r * (NT_NODES + 1);
      ab.r[0].q    = qbf + (size_t)dt * NF;
      ab.r[0].kraw = kbf1;
      ab.r[0].vraw = vbf1;
      ab.r[0].Arel = a_rel + (size_t)(l * NRL + r) * NH * HD * HD;
      ab.r[0].Mrel = m_rel + (size_t)(l * NRL + r) * NH * HD * HD;
      ab.r[0].prel = p_rel + (size_t)(l * NRL + r) * NH;
      ab.r[0].agg  = agg + (size_t)dt * NF;
      ab.r[0].accum = 1;
      attn_fused<<<dim3((NT_NODES + 3) / 4, 1), 256, 0, stream>>>(ab);
    }

    // out: hs_new[t] = a_s*(gelu(agg[t]) @ a_w + a_b) + (1-a_s)*hs[t]
    // writes fp32 over the (dead) bf16 q scratch
    {
      GemmBatch gb{};
      for (int t = 0; t < 3; t++) {
        gb.t[t].A = agg + (size_t)t * NF;
        gb.t[t].W = a_w + (size_t)(l * NTY + t) * FDIM * FDIM;
        gb.t[t].bias = a_b + (size_t)(l * NTY + t) * FDIM;
        gb.t[t].C = alt + (size_t)t * NF;
        gb.t[t].oldh = cur + (size_t)t * NF;
        gb.t[t].skipp = skip + (size_t)(l * NTY + t);
      }
      gemm_f32<1, 1, 0, 0><<<dim3(gemm_gx, 1, 3), 256, 0, stream>>>(gb, NT_NODES);
    }
    float* tmp = cur; cur = alt; alt = tmp;
  }

  // scatter per-type rows back to global node order
  const int NN = 3 * NT_NODES;
  scatter_out<<<dim3((NN * 32 + 255) / 256), 256, 0, stream>>>(
      cur, cur + NF, cur + 2 * NF, ntype, out, NN);
}

// Round 7
// 836.349 us; speedup vs baseline: 1.3679x; 1.3679x over previous
//
#include <hip/hip_runtime.h>
#include <math.h>

#define NT_NODES 30000
#define NE_EDGES 200000
#define NTY 3
#define NRL 4
#define NLY 2
#define NH 8
#define HD 16
#define FDIM 128
#define SCAN_BLOCKS 118   // ceil(30000/256)

typedef unsigned short u16;
typedef unsigned int u32;

__device__ __forceinline__ float bf2f(u16 u) {
  return __uint_as_float(((u32)u) << 16);
}
__device__ __forceinline__ u16 f2bf(float f) {   // RNE
  u32 u = __float_as_uint(f);
  return (u16)((u + 0x7FFFu + ((u >> 16) & 1u)) >> 16);
}

// ---------------------------------------------------------------- GEMM ------
struct GemmTask {
  const float* A; const float* W; const float* bias; float* C;
  const float* oldh; const float* skipp;
};
struct GemmBatch { GemmTask t[7]; };

__device__ __forceinline__ float gelu_f(float x) {
  return 0.5f * x * (1.f + erff(x * 0.7071067811865475f));
}

// C[M,128] = epi(preA(A)[M,128] @ W[128,128] + bias)
template<int GELU_A, int EPI_SKIP, int RELU, int BF16_OUT>
__global__ __launch_bounds__(256) void gemm_f32(GemmBatch gb, int M) {
  const GemmTask tk = gb.t[blockIdx.z];
  const int tid = threadIdx.x;
  const int tx2 = tid & 15;    // col group of 8
  const int ty2 = tid >> 4;    // row group of 4
  const int row0 = blockIdx.x * 64;

  __shared__ float AsT[32][64];   // transposed A chunk [k][row]
  __shared__ float Bs[32][128];   // B chunk [k][col]

  float acc[4][8];
  #pragma unroll
  for (int i = 0; i < 4; i++)
    #pragma unroll
    for (int j = 0; j < 8; j++) acc[i][j] = 0.f;

  for (int k0 = 0; k0 < FDIM; k0 += 32) {
    #pragma unroll
    for (int i = 0; i < 2; i++) {
      int slot = tid + 256 * i;         // 0..511
      int r = slot >> 3, f4 = slot & 7;
      int grow = row0 + r;
      float4 v = make_float4(0.f, 0.f, 0.f, 0.f);
      if (grow < M) v = *(const float4*)(tk.A + (size_t)grow * FDIM + k0 + f4 * 4);
      if (GELU_A) { v.x = gelu_f(v.x); v.y = gelu_f(v.y); v.z = gelu_f(v.z); v.w = gelu_f(v.w); }
      AsT[f4 * 4 + 0][r] = v.x;
      AsT[f4 * 4 + 1][r] = v.y;
      AsT[f4 * 4 + 2][r] = v.z;
      AsT[f4 * 4 + 3][r] = v.w;
    }
    #pragma unroll
    for (int i = 0; i < 4; i++) {
      int slot = tid + 256 * i;         // 0..1023
      int r = slot >> 5, f4 = slot & 31;
      float4 v = *(const float4*)(tk.W + (size_t)(k0 + r) * FDIM + f4 * 4);
      *(float4*)(&Bs[r][f4 * 4]) = v;
    }
    __syncthreads();
    #pragma unroll
    for (int kk = 0; kk < 32; kk++) {
      float4 a4 = *(const float4*)(&AsT[kk][ty2 * 4]);
      float4 b0 = *(const float4*)(&Bs[kk][tx2 * 8]);
      float4 b1 = *(const float4*)(&Bs[kk][tx2 * 8 + 4]);
      const float av[4] = {a4.x, a4.y, a4.z, a4.w};
      #pragma unroll
      for (int i = 0; i < 4; i++) {
        acc[i][0] += av[i] * b0.x; acc[i][1] += av[i] * b0.y;
        acc[i][2] += av[i] * b0.z; acc[i][3] += av[i] * b0.w;
        acc[i][4] += av[i] * b1.x; acc[i][5] += av[i] * b1.y;
        acc[i][6] += av[i] * b1.z; acc[i][7] += av[i] * b1.w;
      }
    }
    __syncthreads();
  }

  float4 bias0 = *(const float4*)(tk.bias + tx2 * 8);
  float4 bias1 = *(const float4*)(tk.bias + tx2 * 8 + 4);
  float a_s = 0.f;
  if (EPI_SKIP) a_s = 1.f / (1.f + expf(-tk.skipp[0]));

  #pragma unroll
  for (int i = 0; i < 4; i++) {
    int grow = row0 + ty2 * 4 + i;
    if (grow >= M) continue;
    float o[8];
    o[0] = acc[i][0] + bias0.x; o[1] = acc[i][1] + bias0.y;
    o[2] = acc[i][2] + bias0.z; o[3] = acc[i][3] + bias0.w;
    o[4] = acc[i][4] + bias1.x; o[5] = acc[i][5] + bias1.y;
    o[6] = acc[i][6] + bias1.z; o[7] = acc[i][7] + bias1.w;
    if (RELU) {
      #pragma unroll
      for (int j = 0; j < 8; j++) o[j] = fmaxf(o[j], 0.f);
    }
    if (EPI_SKIP) {
      const float* hp = tk.oldh + (size_t)grow * FDIM + tx2 * 8;
      float4 h0 = *(const float4*)(hp);
      float4 h1 = *(const float4*)(hp + 4);
      float b_s = 1.f - a_s;
      o[0] = a_s * o[0] + b_s * h0.x; o[1] = a_s * o[1] + b_s * h0.y;
      o[2] = a_s * o[2] + b_s * h0.z; o[3] = a_s * o[3] + b_s * h0.w;
      o[4] = a_s * o[4] + b_s * h1.x; o[5] = a_s * o[5] + b_s * h1.y;
      o[6] = a_s * o[6] + b_s * h1.z; o[7] = a_s * o[7] + b_s * h1.w;
    }
    if (BF16_OUT) {
      u32 p0 = (u32)f2bf(o[0]) | ((u32)f2bf(o[1]) << 16);
      u32 p1 = (u32)f2bf(o[2]) | ((u32)f2bf(o[3]) << 16);
      u32 p2 = (u32)f2bf(o[4]) | ((u32)f2bf(o[5]) << 16);
      u32 p3 = (u32)f2bf(o[6]) | ((u32)f2bf(o[7]) << 16);
      u16* cp = ((u16*)tk.C) + (size_t)grow * FDIM + tx2 * 8;
      *(uint4*)cp = make_uint4(p0, p1, p2, p3);
    } else {
      float* cp = tk.C + (size_t)grow * FDIM + tx2 * 8;
      *(float4*)cp = make_float4(o[0], o[1], o[2], o[3]);
      *(float4*)(cp + 4) = make_float4(o[4], o[5], o[6], o[7]);
    }
  }
}

// ------------------------------------------------------------- CSR build ----
__global__ __launch_bounds__(256) void csr_hist(const int* __restrict__ edge_index,
                                                int* __restrict__ counts) {
  int idx = blockIdx.x * 256 + threadIdx.x;
  if (idx >= NRL * NE_EDGES) return;
  int r = idx / NE_EDGES, e = idx - r * NE_EDGES;
  int d = edge_index[(size_t)(r * 2 + 1) * NE_EDGES + e];
  atomicAdd(&counts[r * NT_NODES + d], 1);
}

// hierarchical scan: block-local -> aux -> add-back
__global__ __launch_bounds__(256) void scan_block(const int* __restrict__ counts,
                                                  int* __restrict__ off,
                                                  int* __restrict__ aux) {
  int r = blockIdx.y, b = blockIdx.x, t = threadIdx.x;
  int i = b * 256 + t;
  int v = (i < NT_NODES) ? counts[r * NT_NODES + i] : 0;
  __shared__ int lds[256];
  lds[t] = v;
  __syncthreads();
  #pragma unroll
  for (int dlt = 1; dlt < 256; dlt <<= 1) {
    int x = (t >= dlt) ? lds[t - dlt] : 0;
    __syncthreads();
    lds[t] += x;
    __syncthreads();
  }
  if (i < NT_NODES) off[(size_t)r * (NT_NODES + 1) + i] = lds[t] - v;  // block-local exclusive
  if (t == 255) aux[r * SCAN_BLOCKS + b] = lds[255];
}

__global__ __launch_bounds__(128) void scan_aux(const int* __restrict__ aux,
                                                int* __restrict__ auxe,
                                                int* __restrict__ off) {
  int r = blockIdx.x, t = threadIdx.x;
  __shared__ int lds[128];
  int v = (t < SCAN_BLOCKS) ? aux[r * SCAN_BLOCKS + t] : 0;
  lds[t] = v;
  __syncthreads();
  #pragma unroll
  for (int dlt = 1; dlt < 128; dlt <<= 1) {
    int x = (t >= dlt) ? lds[t - dlt] : 0;
    __syncthreads();
    lds[t] += x;
    __syncthreads();
  }
  if (t < SCAN_BLOCKS) auxe[r * SCAN_BLOCKS + t] = lds[t] - v;   // exclusive
  if (t == 127) off[(size_t)r * (NT_NODES + 1) + NT_NODES] = lds[127];  // grand total
}

__global__ __launch_bounds__(256) void scan_add(const int* __restrict__ auxe,
                                                int* __restrict__ off,
                                                int* __restrict__ cursor) {
  int r = blockIdx.y, b = blockIdx.x, t = threadIdx.x;
  int i = b * 256 + t;
  if (i >= NT_NODES) return;
  int val = off[(size_t)r * (NT_NODES + 1) + i] + auxe[r * SCAN_BLOCKS + b];
  off[(size_t)r * (NT_NODES + 1) + i] = val;
  cursor[r * NT_NODES + i] = val;
}

__global__ __launch_bounds__(256) void csr_scatter(const int* __restrict__ edge_index,
                                                   int* __restrict__ cursor,
                                                   int* __restrict__ csr_src) {
  int idx = blockIdx.x * 256 + threadIdx.x;
  if (idx >= NRL * NE_EDGES) return;
  int r = idx / NE_EDGES, e = idx - r * NE_EDGES;
  int s = edge_index[(size_t)(r * 2 + 0) * NE_EDGES + e];
  int d = edge_index[(size_t)(r * 2 + 1) * NE_EDGES + e];
  int pos = atomicAdd(&cursor[r * NT_NODES + d], 1);
  csr_src[(size_t)r * NE_EDGES + pos] = s;
}

// ---------------------------------------------------- fused attention -------
// One wave per dst node (round-5 layout: lane owns channels {2l,2l+1} as
// ushort2; head h = lane>>3, 8-lane dot reduce = 3 shfl_xor). Edge loop is
// manually batched 4/2/1: 4 wave-uniform CSR indices -> 8 independent K/V
// gathers in flight -> serial latency chain per node drops ~6.7 -> ~2.5.
struct AttnRel {
  const int* csr_src; const int* off;
  const u16* q;        // bf16 Q of dst type [N,128]
  const u16* kraw;     // bf16 raw K of src type [N,128]
  const u16* vraw;     // bf16 raw V of src type [N,128]
  const float* Arel;   // [8][16][16]
  const float* Mrel;   // [8][16][16]
  const float* prel;   // [8]
  float* agg;          // agg of dst type [N,128]
  int accum;
};
struct AttnBatch { AttnRel r[3]; };

__global__ __launch_bounds__(256) void attn_fused(AttnBatch ab) {
  const AttnRel rp = ab.r[blockIdx.y];
  const int wave = threadIdx.x >> 6;
  const int lane = threadIdx.x & 63;
  const int d = blockIdx.x * 4 + wave;
  if (d >= NT_NODES) return;
  const int h = lane >> 3;         // head 0..7
  const int el = lane & 7;         // pair index within head (channels 2el,2el+1)
  const int grp = h << 3;          // first lane of this head's group

  // ---- q' = (A_h @ q_h) * p_h/4 via shfl within 8-lane head groups ----
  ushort2 qu = ((const ushort2*)rp.q)[(size_t)d * 64 + lane];
  float q0 = bf2f(qu.x), q1 = bf2f(qu.y);
  const float* A = rp.Arel + (size_t)h * 256;
  float qp0 = 0.f, qp1 = 0.f;
  #pragma unroll
  for (int ee = 0; ee < 8; ee++) {
    float qa = __shfl(q0, grp + ee, 64);     // q_e, e=2ee
    float qb = __shfl(q1, grp + ee, 64);     // q_e, e=2ee+1
    qp0 += A[(2 * el) * 16 + 2 * ee] * qa + A[(2 * el) * 16 + 2 * ee + 1] * qb;
    qp1 += A[(2 * el + 1) * 16 + 2 * ee] * qa + A[(2 * el + 1) * 16 + 2 * ee + 1] * qb;
  }
  float sc = rp.prel[h] * 0.25f;
  qp0 *= sc; qp1 *= sc;

  // ---- edge loop: 4/2/1 batches, gathers issued together ----
  const ushort2* Kp = (const ushort2*)rp.kraw;
  const ushort2* Vp = (const ushort2*)rp.vraw;
  const int* __restrict__ cs = rp.csr_src;
  int lo = rp.off[d], hi = rp.off[d + 1];
  float acc0 = 0.f, acc1 = 0.f, ssum = 0.f;
  int pos = lo;
  for (; pos + 4 <= hi; pos += 4) {
    int s0 = cs[pos + 0], s1 = cs[pos + 1], s2 = cs[pos + 2], s3 = cs[pos + 3];
    ushort2 k0 = Kp[(size_t)s0 * 64 + lane], k1 = Kp[(size_t)s1 * 64 + lane];
    ushort2 k2 = Kp[(size_t)s2 * 64 + lane], k3 = Kp[(size_t)s3 * 64 + lane];
    ushort2 v0 = Vp[(size_t)s0 * 64 + lane], v1 = Vp[(size_t)s1 * 64 + lane];
    ushort2 v2 = Vp[(size_t)s2 * 64 + lane], v3 = Vp[(size_t)s3 * 64 + lane];
    float p0 = qp0 * bf2f(k0.x) + qp1 * bf2f(k0.y);
    float p1 = qp0 * bf2f(k1.x) + qp1 * bf2f(k1.y);
    float p2 = qp0 * bf2f(k2.x) + qp1 * bf2f(k2.y);
    float p3 = qp0 * bf2f(k3.x) + qp1 * bf2f(k3.y);
    p0 += __shfl_xor(p0, 1, 64); p1 += __shfl_xor(p1, 1, 64);
    p2 += __shfl_xor(p2, 1, 64); p3 += __shfl_xor(p3, 1, 64);
    p0 += __shfl_xor(p0, 2, 64); p1 += __shfl_xor(p1, 2, 64);
    p2 += __shfl_xor(p2, 2, 64); p3 += __shfl_xor(p3, 2, 64);
    p0 += __shfl_xor(p0, 4, 64); p1 += __shfl_xor(p1, 4, 64);
    p2 += __shfl_xor(p2, 4, 64); p3 += __shfl_xor(p3, 4, 64);
    float e0 = __expf(p0), e1 = __expf(p1), e2 = __expf(p2), e3 = __expf(p3);
    acc0 += e0 * bf2f(v0.x) + e1 * bf2f(v1.x) + e2 * bf2f(v2.x) + e3 * bf2f(v3.x);
    acc1 += e0 * bf2f(v0.y) + e1 * bf2f(v1.y) + e2 * bf2f(v2.y) + e3 * bf2f(v3.y);
    ssum += (e0 + e1) + (e2 + e3);
  }
  if (pos + 2 <= hi) {
    int s0 = cs[pos + 0], s1 = cs[pos + 1];
    ushort2 k0 = Kp[(size_t)s0 * 64 + lane], k1 = Kp[(size_t)s1 * 64 + lane];
    ushort2 v0 = Vp[(size_t)s0 * 64 + lane], v1 = Vp[(size_t)s1 * 64 + lane];
    float p0 = qp0 * bf2f(k0.x) + qp1 * bf2f(k0.y);
    float p1 = qp0 * bf2f(k1.x) + qp1 * bf2f(k1.y);
    p0 += __shfl_xor(p0, 1, 64); p1 += __shfl_xor(p1, 1, 64);
    p0 += __shfl_xor(p0, 2, 64); p1 += __shfl_xor(p1, 2, 64);
    p0 += __shfl_xor(p0, 4, 64); p1 += __shfl_xor(p1, 4, 64);
    float e0 = __expf(p0), e1 = __expf(p1);
    acc0 += e0 * bf2f(v0.x) + e1 * bf2f(v1.x);
    acc1 += e0 * bf2f(v0.y) + e1 * bf2f(v1.y);
    ssum += e0 + e1;
    pos += 2;
  }
  if (pos < hi) {
    int s0 = cs[pos];
    ushort2 k0 = Kp[(size_t)s0 * 64 + lane];
    ushort2 v0 = Vp[(size_t)s0 * 64 + lane];
    float p0 = qp0 * bf2f(k0.x) + qp1 * bf2f(k0.y);
    p0 += __shfl_xor(p0, 1, 64);
    p0 += __shfl_xor(p0, 2, 64);
    p0 += __shfl_xor(p0, 4, 64);
    float e0 = __expf(p0);
    acc0 += e0 * bf2f(v0.x);
    acc1 += e0 * bf2f(v0.y);
    ssum += e0;
  }
  float inv = 1.f / (ssum + 1e-16f);
  float S0 = acc0 * inv, S1 = acc1 * inv;   // raw-V aggregate, d2 = 2el, 2el+1

  // ---- apply M_rel: out_j = sum_d2 S[d2] * M[h][d2][j], j = 2el, 2el+1 ----
  const float* M = rp.Mrel + (size_t)h * 256;
  float o0 = 0.f, o1 = 0.f;
  #pragma unroll
  for (int dd = 0; dd < 8; dd++) {
    float sa = __shfl(S0, grp + dd, 64);     // S_{2dd}
    float sb = __shfl(S1, grp + dd, 64);     // S_{2dd+1}
    o0 += sa * M[(2 * dd) * 16 + 2 * el] + sb * M[(2 * dd + 1) * 16 + 2 * el];
    o1 += sa * M[(2 * dd) * 16 + 2 * el + 1] + sb * M[(2 * dd + 1) * 16 + 2 * el + 1];
  }
  float* ap = rp.agg + (size_t)d * FDIM + 2 * lane;
  if (rp.accum) {
    float2 old = *(float2*)ap;
    *(float2*)ap = make_float2(old.x + o0, old.y + o1);
  } else {
    *(float2*)ap = make_float2(o0, o1);
  }
}

// ---------------------------------------------------------------- scatter ---
__global__ __launch_bounds__(256) void scatter_out(const float* h0, const float* h1,
                                                   const float* h2, const int* ntype,
                                                   float* out, int NN) {
  int idx = blockIdx.x * 256 + threadIdx.x;
  if (idx >= NN * 32) return;
  int i = idx >> 5, c4 = idx & 31;
  int t = ntype[i];
  const float* hp = (t == 0) ? h0 : ((t == 1) ? h1 : h2);
  int local = i - t * NT_NODES;   // node_type_argmax is contiguous blocks per type
  ((float4*)out)[idx] = ((const float4*)hp)[(size_t)local * 32 + c4];
}

// ------------------------------------------------------------------- host ---
static const int ESRC[NRL] = {0, 0, 1, 0};
static const int EDST[NRL] = {0, 1, 0, 2};

extern "C" void kernel_launch(void* const* d_in, const int* in_sizes, int n_in,
                              void* d_out, int out_size, void* d_ws, size_t ws_size,
                              hipStream_t stream) {
  const float* x[3] = {(const float*)d_in[0], (const float*)d_in[1], (const float*)d_in[2]};
  const float* lin_w = (const float*)d_in[4];
  const float* lin_b = (const float*)d_in[5];
  const float* k_w   = (const float*)d_in[6];
  const float* k_b   = (const float*)d_in[7];
  const float* q_w   = (const float*)d_in[8];
  const float* q_b   = (const float*)d_in[9];
  const float* v_w   = (const float*)d_in[10];
  const float* v_b   = (const float*)d_in[11];
  const float* a_w   = (const float*)d_in[12];
  const float* a_b   = (const float*)d_in[13];
  const float* skip  = (const float*)d_in[14];
  const float* a_rel = (const float*)d_in[15];
  const float* m_rel = (const float*)d_in[16];
  const float* p_rel = (const float*)d_in[17];
  const int* edge_index = (const int*)d_in[18];
  const int* ntype   = (const int*)d_in[19];
  float* out = (float*)d_out;

  const size_t NF = (size_t)NT_NODES * FDIM;   // 3.84M elems per [N,128]
  float* p = (float*)d_ws;
  auto alloc = [&](size_t n) { float* r = p; p += n; return r; };
  float* bufA = alloc(3 * NF);                    // h (ping)
  float* bufB = alloc(3 * NF);                    // h (pong); bf16 Q aliases alt
  float* agg  = alloc(3 * NF);                    // edge aggregation (raw-V space)
  u16* kbf0 = (u16*)alloc(NF / 2);                // bf16 K, src type 0
  u16* vbf0 = (u16*)alloc(NF / 2);                // bf16 V, src type 0
  u16* kbf1 = (u16*)alloc(NF / 2);                // bf16 K, src type 1
  u16* vbf1 = (u16*)alloc(NF / 2);                // bf16 V, src type 1
  int* counts  = (int*)(p);                       // [4][N]
  int* cursor  = counts + NRL * NT_NODES;         // [4][N]
  int* offsets = cursor + NRL * NT_NODES;         // [4][N+1]
  int* aux     = offsets + NRL * (NT_NODES + 1);  // [4][118]
  int* auxe    = aux + NRL * SCAN_BLOCKS;         // [4][118]
  int* csr_src = auxe + NRL * SCAN_BLOCKS;        // [4][E]

  const int gemm_gx = (NT_NODES + 63) / 64;   // 469

  // ---- CSR build (edge_index fixed within a call; reused by both layers) ----
  hipMemsetAsync(counts, 0, NRL * NT_NODES * sizeof(int), stream);
  csr_hist<<<dim3((NRL * NE_EDGES + 255) / 256), 256, 0, stream>>>(edge_index, counts);
  scan_block<<<dim3(SCAN_BLOCKS, NRL), 256, 0, stream>>>(counts, offsets, aux);
  scan_aux<<<dim3(NRL), 128, 0, stream>>>(aux, auxe, offsets);
  scan_add<<<dim3(SCAN_BLOCKS, NRL), 256, 0, stream>>>(auxe, offsets, cursor);
  csr_scatter<<<dim3((NRL * NE_EDGES + 255) / 256), 256, 0, stream>>>(edge_index, cursor, csr_src);

  // input projection: hs[t] = relu(x_t @ lin_w[t] + lin_b[t])
  {
    GemmBatch gb{};
    for (int t = 0; t < 3; t++) {
      gb.t[t].A = x[t];
      gb.t[t].W = lin_w + (size_t)t * FDIM * FDIM;
      gb.t[t].bias = lin_b + (size_t)t * FDIM;
      gb.t[t].C = bufA + (size_t)t * NF;
    }
    gemm_f32<0, 0, 1, 0><<<dim3(gemm_gx, 1, 3), 256, 0, stream>>>(gb, NT_NODES);
  }

  float* cur = bufA;   // current h (fp32)
  float* alt = bufB;   // bf16 Q scratch now, fp32 next-h later
  for (int l = 0; l < NLY; l++) {
    u16* qbf = (u16*)alt;

    // Q for all 3 types + raw K/V for src types 0 and 1 — all bf16, one launch
    {
      GemmBatch gb{};
      for (int t = 0; t < 3; t++) {
        gb.t[t].A = cur + (size_t)t * NF;
        gb.t[t].W = q_w + (size_t)(l * NTY + t) * FDIM * FDIM;
        gb.t[t].bias = q_b + (size_t)(l * NTY + t) * FDIM;
        gb.t[t].C = (float*)(qbf + (size_t)t * NF);
      }
      gb.t[3].A = cur;                                   // src type 0
      gb.t[3].W = k_w + (size_t)(l * NTY + 0) * FDIM * FDIM;
      gb.t[3].bias = k_b + (size_t)(l * NTY + 0) * FDIM;
      gb.t[3].C = (float*)kbf0;
      gb.t[4].A = cur;
      gb.t[4].W = v_w + (size_t)(l * NTY + 0) * FDIM * FDIM;
      gb.t[4].bias = v_b + (size_t)(l * NTY + 0) * FDIM;
      gb.t[4].C = (float*)vbf0;
      gb.t[5].A = cur + NF;                              // src type 1
      gb.t[5].W = k_w + (size_t)(l * NTY + 1) * FDIM * FDIM;
      gb.t[5].bias = k_b + (size_t)(l * NTY + 1) * FDIM;
      gb.t[5].C = (float*)kbf1;
      gb.t[6].A = cur + NF;
      gb.t[6].W = v_w + (size_t)(l * NTY + 1) * FDIM * FDIM;
      gb.t[6].bias = v_b + (size_t)(l * NTY + 1) * FDIM;
      gb.t[6].C = (float*)vbf1;
      gemm_f32<0, 0, 0, 1><<<dim3(gemm_gx, 1, 7), 256, 0, stream>>>(gb, NT_NODES);
    }

    // attention launch A: relations {0,1,3} (src type 0; dst types 0,1,2
    // disjoint -> agg overwritten, no memset needed)
    {
      AttnBatch ab{};
      const int rels[3] = {0, 1, 3};
      for (int j = 0; j < 3; j++) {
        int r = rels[j], dt = EDST[r];
        ab.r[j].csr_src = csr_src + (size_t)r * NE_EDGES;
        ab.r[j].off  = offsets + (size_t)r * (NT_NODES + 1);
        ab.r[j].q    = qbf + (size_t)dt * NF;
        ab.r[j].kraw = kbf0;
        ab.r[j].vraw = vbf0;
        ab.r[j].Arel = a_rel + (size_t)(l * NRL + r) * NH * HD * HD;
        ab.r[j].Mrel = m_rel + (size_t)(l * NRL + r) * NH * HD * HD;
        ab.r[j].prel = p_rel + (size_t)(l * NRL + r) * NH;
        ab.r[j].agg  = agg + (size_t)dt * NF;
        ab.r[j].accum = 0;
      }
      attn_fused<<<dim3((NT_NODES + 3) / 4, 3), 256, 0, stream>>>(ab);
    }

    // attention launch B: relation {2} (src type 1, dst type 0, accumulate)
    {
      AttnBatch ab{};
      int r = 2, dt = EDST[r];
      ab.r[0].csr_src = csr_src + (size_t)r * NE_EDGES;
      ab.r[0].off  = offsets + (size_t)r * (NT_NODES + 1);
      ab.r[0].q    = qbf + (size_t)dt * NF;
      ab.r[0].kraw = kbf1;
      ab.r[0].vraw = vbf1;
      ab.r[0].Arel = a_rel + (size_t)(l * NRL + r) * NH * HD * HD;
      ab.r[0].Mrel = m_rel + (size_t)(l * NRL + r) * NH * HD * HD;
      ab.r[0].prel = p_rel + (size_t)(l * NRL + r) * NH;
      ab.r[0].agg  = agg + (size_t)dt * NF;
      ab.r[0].accum = 1;
      attn_fused<<<dim3((NT_NODES + 3) / 4, 1), 256, 0, stream>>>(ab);
    }

    // out: hs_new[t] = a_s*(gelu(agg[t]) @ a_w + a_b) + (1-a_s)*hs[t]
    // writes fp32 over the (dead) bf16 q scratch
    {
      GemmBatch gb{};
      for (int t = 0; t < 3; t++) {
        gb.t[t].A = agg + (size_t)t * NF;
        gb.t[t].W = a_w + (size_t)(l * NTY + t) * FDIM * FDIM;
        gb.t[t].bias = a_b + (size_t)(l * NTY + t) * FDIM;
        gb.t[t].C = alt + (size_t)t * NF;
        gb.t[t].oldh = cur + (size_t)t * NF;
        gb.t[t].skipp = skip + (size_t)(l * NTY + t);
      }
      gemm_f32<1, 1, 0, 0><<<dim3(gemm_gx, 1, 3), 256, 0, stream>>>(gb, NT_NODES);
    }
    float* tmp = cur; cur = alt; alt = tmp;
  }

  // scatter per-type rows back to global node order
  const int NN = 3 * NT_NODES;
  scatter_out<<<dim3((NN * 32 + 255) / 256), 256, 0, stream>>>(
      cur, cur + NF, cur + 2 * NF, ntype, out, NN);
}

// Round 8
// 822.553 us; speedup vs baseline: 1.3908x; 1.0168x over previous
//
#include <hip/hip_runtime.h>
#include <math.h>

#define NT_NODES 30000
#define NE_EDGES 200000
#define NTY 3
#define NRL 4
#define NLY 2
#define NH 8
#define HD 16
#define FDIM 128
#define SCAN_BLOCKS 118   // ceil(30000/256)

typedef unsigned short u16;
typedef unsigned int u32;

__device__ __forceinline__ float bf2f(u16 u) {
  return __uint_as_float(((u32)u) << 16);
}
__device__ __forceinline__ u16 f2bf(float f) {   // RNE
  u32 u = __float_as_uint(f);
  return (u16)((u + 0x7FFFu + ((u >> 16) & 1u)) >> 16);
}

// ---------------------------------------------------------------- GEMM ------
struct GemmTask {
  const float* A; const float* W; const float* bias; float* C;
  const float* oldh; const float* skipp;
  const float* A2;   // optional second A operand summed before GELU (type-0 out)
};
struct GemmBatch { GemmTask t[7]; };

__device__ __forceinline__ float gelu_f(float x) {
  return 0.5f * x * (1.f + erff(x * 0.7071067811865475f));
}

// C[M,128] = epi(preA(A [+A2])[M,128] @ W[128,128] + bias)
template<int GELU_A, int EPI_SKIP, int RELU, int BF16_OUT>
__global__ __launch_bounds__(256) void gemm_f32(GemmBatch gb, int M) {
  const GemmTask tk = gb.t[blockIdx.z];
  const int tid = threadIdx.x;
  const int tx2 = tid & 15;    // col group of 8
  const int ty2 = tid >> 4;    // row group of 4
  const int row0 = blockIdx.x * 64;

  __shared__ float AsT[32][64];   // transposed A chunk [k][row]
  __shared__ float Bs[32][128];   // B chunk [k][col]

  float acc[4][8];
  #pragma unroll
  for (int i = 0; i < 4; i++)
    #pragma unroll
    for (int j = 0; j < 8; j++) acc[i][j] = 0.f;

  for (int k0 = 0; k0 < FDIM; k0 += 32) {
    #pragma unroll
    for (int i = 0; i < 2; i++) {
      int slot = tid + 256 * i;         // 0..511
      int r = slot >> 3, f4 = slot & 7;
      int grow = row0 + r;
      float4 v = make_float4(0.f, 0.f, 0.f, 0.f);
      if (grow < M) {
        v = *(const float4*)(tk.A + (size_t)grow * FDIM + k0 + f4 * 4);
        if (GELU_A && tk.A2) {
          float4 v2 = *(const float4*)(tk.A2 + (size_t)grow * FDIM + k0 + f4 * 4);
          v.x += v2.x; v.y += v2.y; v.z += v2.z; v.w += v2.w;
        }
      }
      if (GELU_A) { v.x = gelu_f(v.x); v.y = gelu_f(v.y); v.z = gelu_f(v.z); v.w = gelu_f(v.w); }
      AsT[f4 * 4 + 0][r] = v.x;
      AsT[f4 * 4 + 1][r] = v.y;
      AsT[f4 * 4 + 2][r] = v.z;
      AsT[f4 * 4 + 3][r] = v.w;
    }
    #pragma unroll
    for (int i = 0; i < 4; i++) {
      int slot = tid + 256 * i;         // 0..1023
      int r = slot >> 5, f4 = slot & 31;
      float4 v = *(const float4*)(tk.W + (size_t)(k0 + r) * FDIM + f4 * 4);
      *(float4*)(&Bs[r][f4 * 4]) = v;
    }
    __syncthreads();
    #pragma unroll
    for (int kk = 0; kk < 32; kk++) {
      float4 a4 = *(const float4*)(&AsT[kk][ty2 * 4]);
      float4 b0 = *(const float4*)(&Bs[kk][tx2 * 8]);
      float4 b1 = *(const float4*)(&Bs[kk][tx2 * 8 + 4]);
      const float av[4] = {a4.x, a4.y, a4.z, a4.w};
      #pragma unroll
      for (int i = 0; i < 4; i++) {
        acc[i][0] += av[i] * b0.x; acc[i][1] += av[i] * b0.y;
        acc[i][2] += av[i] * b0.z; acc[i][3] += av[i] * b0.w;
        acc[i][4] += av[i] * b1.x; acc[i][5] += av[i] * b1.y;
        acc[i][6] += av[i] * b1.z; acc[i][7] += av[i] * b1.w;
      }
    }
    __syncthreads();
  }

  float4 bias0 = *(const float4*)(tk.bias + tx2 * 8);
  float4 bias1 = *(const float4*)(tk.bias + tx2 * 8 + 4);
  float a_s = 0.f;
  if (EPI_SKIP) a_s = 1.f / (1.f + expf(-tk.skipp[0]));

  #pragma unroll
  for (int i = 0; i < 4; i++) {
    int grow = row0 + ty2 * 4 + i;
    if (grow >= M) continue;
    float o[8];
    o[0] = acc[i][0] + bias0.x; o[1] = acc[i][1] + bias0.y;
    o[2] = acc[i][2] + bias0.z; o[3] = acc[i][3] + bias0.w;
    o[4] = acc[i][4] + bias1.x; o[5] = acc[i][5] + bias1.y;
    o[6] = acc[i][6] + bias1.z; o[7] = acc[i][7] + bias1.w;
    if (RELU) {
      #pragma unroll
      for (int j = 0; j < 8; j++) o[j] = fmaxf(o[j], 0.f);
    }
    if (EPI_SKIP) {
      const float* hp = tk.oldh + (size_t)grow * FDIM + tx2 * 8;
      float4 h0 = *(const float4*)(hp);
      float4 h1 = *(const float4*)(hp + 4);
      float b_s = 1.f - a_s;
      o[0] = a_s * o[0] + b_s * h0.x; o[1] = a_s * o[1] + b_s * h0.y;
      o[2] = a_s * o[2] + b_s * h0.z; o[3] = a_s * o[3] + b_s * h0.w;
      o[4] = a_s * o[4] + b_s * h1.x; o[5] = a_s * o[5] + b_s * h1.y;
      o[6] = a_s * o[6] + b_s * h1.z; o[7] = a_s * o[7] + b_s * h1.w;
    }
    if (BF16_OUT) {
      u32 p0 = (u32)f2bf(o[0]) | ((u32)f2bf(o[1]) << 16);
      u32 p1 = (u32)f2bf(o[2]) | ((u32)f2bf(o[3]) << 16);
      u32 p2 = (u32)f2bf(o[4]) | ((u32)f2bf(o[5]) << 16);
      u32 p3 = (u32)f2bf(o[6]) | ((u32)f2bf(o[7]) << 16);
      u16* cp = ((u16*)tk.C) + (size_t)grow * FDIM + tx2 * 8;
      *(uint4*)cp = make_uint4(p0, p1, p2, p3);
    } else {
      float* cp = tk.C + (size_t)grow * FDIM + tx2 * 8;
      *(float4*)cp = make_float4(o[0], o[1], o[2], o[3]);
      *(float4*)(cp + 4) = make_float4(o[4], o[5], o[6], o[7]);
    }
  }
}

// ------------------------------------------------------------- CSR build ----
__global__ __launch_bounds__(256) void csr_hist(const int* __restrict__ edge_index,
                                                int* __restrict__ counts) {
  int idx = blockIdx.x * 256 + threadIdx.x;
  if (idx >= NRL * NE_EDGES) return;
  int r = idx / NE_EDGES, e = idx - r * NE_EDGES;
  int d = edge_index[(size_t)(r * 2 + 1) * NE_EDGES + e];
  atomicAdd(&counts[r * NT_NODES + d], 1);
}

// hierarchical scan: block-local -> aux -> add-back
__global__ __launch_bounds__(256) void scan_block(const int* __restrict__ counts,
                                                  int* __restrict__ off,
                                                  int* __restrict__ aux) {
  int r = blockIdx.y, b = blockIdx.x, t = threadIdx.x;
  int i = b * 256 + t;
  int v = (i < NT_NODES) ? counts[r * NT_NODES + i] : 0;
  __shared__ int lds[256];
  lds[t] = v;
  __syncthreads();
  #pragma unroll
  for (int dlt = 1; dlt < 256; dlt <<= 1) {
    int x = (t >= dlt) ? lds[t - dlt] : 0;
    __syncthreads();
    lds[t] += x;
    __syncthreads();
  }
  if (i < NT_NODES) off[(size_t)r * (NT_NODES + 1) + i] = lds[t] - v;  // block-local exclusive
  if (t == 255) aux[r * SCAN_BLOCKS + b] = lds[255];
}

__global__ __launch_bounds__(128) void scan_aux(const int* __restrict__ aux,
                                                int* __restrict__ auxe,
                                                int* __restrict__ off) {
  int r = blockIdx.x, t = threadIdx.x;
  __shared__ int lds[128];
  int v = (t < SCAN_BLOCKS) ? aux[r * SCAN_BLOCKS + t] : 0;
  lds[t] = v;
  __syncthreads();
  #pragma unroll
  for (int dlt = 1; dlt < 128; dlt <<= 1) {
    int x = (t >= dlt) ? lds[t - dlt] : 0;
    __syncthreads();
    lds[t] += x;
    __syncthreads();
  }
  if (t < SCAN_BLOCKS) auxe[r * SCAN_BLOCKS + t] = lds[t] - v;   // exclusive
  if (t == 127) off[(size_t)r * (NT_NODES + 1) + NT_NODES] = lds[127];  // grand total
}

__global__ __launch_bounds__(256) void scan_add(const int* __restrict__ auxe,
                                                int* __restrict__ off,
                                                int* __restrict__ cursor) {
  int r = blockIdx.y, b = blockIdx.x, t = threadIdx.x;
  int i = b * 256 + t;
  if (i >= NT_NODES) return;
  int val = off[(size_t)r * (NT_NODES + 1) + i] + auxe[r * SCAN_BLOCKS + b];
  off[(size_t)r * (NT_NODES + 1) + i] = val;
  cursor[r * NT_NODES + i] = val;
}

__global__ __launch_bounds__(256) void csr_scatter(const int* __restrict__ edge_index,
                                                   int* __restrict__ cursor,
                                                   int* __restrict__ csr_src) {
  int idx = blockIdx.x * 256 + threadIdx.x;
  if (idx >= NRL * NE_EDGES) return;
  int r = idx / NE_EDGES, e = idx - r * NE_EDGES;
  int s = edge_index[(size_t)(r * 2 + 0) * NE_EDGES + e];
  int d = edge_index[(size_t)(r * 2 + 1) * NE_EDGES + e];
  int pos = atomicAdd(&cursor[r * NT_NODES + d], 1);
  csr_src[(size_t)r * NE_EDGES + pos] = s;
}

// zero the 8-int slack after csr_src so unconditional 8-batch reads are safe
__global__ void csr_pad(int* __restrict__ pad) {
  if (threadIdx.x < 8) pad[threadIdx.x] = 0;
}

// ---------------------------------------------------- fused attention -------
// One wave per dst node (lane owns channels {2l,2l+1} as ushort2; head
// h = lane>>3, 8-lane dot reduce = 3 shfl_xor). Edge loop: UNIFORM 8-edge
// batches -> 16 independent gathers in flight per chain step. Tail edges
// read csr_src unconditionally (zero-filled slack) and are masked ev=0.
// All 4 relations in one launch (grid.y); rel2 writes separate aggX.
struct AttnRel {
  const int* csr_src; const int* off;
  const u16* q;        // bf16 Q of dst type [N,128]
  const u16* kraw;     // bf16 raw K of src type [N,128]
  const u16* vraw;     // bf16 raw V of src type [N,128]
  const float* Arel;   // [8][16][16]
  const float* Mrel;   // [8][16][16]
  const float* prel;   // [8]
  float* agg;          // output [N,128] (overwritten)
};
struct AttnBatch { AttnRel r[4]; };

__global__ __launch_bounds__(256) void attn_fused(AttnBatch ab) {
  const AttnRel rp = ab.r[blockIdx.y];
  const int wave = threadIdx.x >> 6;
  const int lane = threadIdx.x & 63;
  const int d = blockIdx.x * 4 + wave;
  if (d >= NT_NODES) return;
  const int h = lane >> 3;         // head 0..7
  const int el = lane & 7;         // pair index within head (channels 2el,2el+1)
  const int grp = h << 3;          // first lane of this head's group

  // ---- q' = (A_h @ q_h) * p_h/4 via shfl within 8-lane head groups ----
  ushort2 qu = ((const ushort2*)rp.q)[(size_t)d * 64 + lane];
  float q0 = bf2f(qu.x), q1 = bf2f(qu.y);
  const float* A = rp.Arel + (size_t)h * 256;
  float qp0 = 0.f, qp1 = 0.f;
  #pragma unroll
  for (int ee = 0; ee < 8; ee++) {
    float qa = __shfl(q0, grp + ee, 64);     // q_e, e=2ee
    float qb = __shfl(q1, grp + ee, 64);     // q_e, e=2ee+1
    qp0 += A[(2 * el) * 16 + 2 * ee] * qa + A[(2 * el) * 16 + 2 * ee + 1] * qb;
    qp1 += A[(2 * el + 1) * 16 + 2 * ee] * qa + A[(2 * el + 1) * 16 + 2 * ee + 1] * qb;
  }
  float sc = rp.prel[h] * 0.25f;
  qp0 *= sc; qp1 *= sc;

  // ---- edge loop: uniform 8-edge batches, 16 gathers in flight ----
  const ushort2* Kp = (const ushort2*)rp.kraw;
  const ushort2* Vp = (const ushort2*)rp.vraw;
  const int* __restrict__ cs = rp.csr_src;
  int lo = rp.off[d], hi = rp.off[d + 1];
  lo = __builtin_amdgcn_readfirstlane(lo);
  hi = __builtin_amdgcn_readfirstlane(hi);
  float acc0 = 0.f, acc1 = 0.f, ssum = 0.f;
  for (int pos = lo; pos < hi; pos += 8) {
    int s0 = cs[pos + 0], s1 = cs[pos + 1], s2 = cs[pos + 2], s3 = cs[pos + 3];
    int s4 = cs[pos + 4], s5 = cs[pos + 5], s6 = cs[pos + 6], s7 = cs[pos + 7];
    ushort2 k0 = Kp[(size_t)s0 * 64 + lane], k1 = Kp[(size_t)s1 * 64 + lane];
    ushort2 k2 = Kp[(size_t)s2 * 64 + lane], k3 = Kp[(size_t)s3 * 64 + lane];
    ushort2 k4 = Kp[(size_t)s4 * 64 + lane], k5 = Kp[(size_t)s5 * 64 + lane];
    ushort2 k6 = Kp[(size_t)s6 * 64 + lane], k7 = Kp[(size_t)s7 * 64 + lane];
    ushort2 v0 = Vp[(size_t)s0 * 64 + lane], v1 = Vp[(size_t)s1 * 64 + lane];
    ushort2 v2 = Vp[(size_t)s2 * 64 + lane], v3 = Vp[(size_t)s3 * 64 + lane];
    ushort2 v4 = Vp[(size_t)s4 * 64 + lane], v5 = Vp[(size_t)s5 * 64 + lane];
    ushort2 v6 = Vp[(size_t)s6 * 64 + lane], v7 = Vp[(size_t)s7 * 64 + lane];
    float p0 = qp0 * bf2f(k0.x) + qp1 * bf2f(k0.y);
    float p1 = qp0 * bf2f(k1.x) + qp1 * bf2f(k1.y);
    float p2 = qp0 * bf2f(k2.x) + qp1 * bf2f(k2.y);
    float p3 = qp0 * bf2f(k3.x) + qp1 * bf2f(k3.y);
    float p4 = qp0 * bf2f(k4.x) + qp1 * bf2f(k4.y);
    float p5 = qp0 * bf2f(k5.x) + qp1 * bf2f(k5.y);
    float p6 = qp0 * bf2f(k6.x) + qp1 * bf2f(k6.y);
    float p7 = qp0 * bf2f(k7.x) + qp1 * bf2f(k7.y);
    p0 += __shfl_xor(p0, 1, 64); p1 += __shfl_xor(p1, 1, 64);
    p2 += __shfl_xor(p2, 1, 64); p3 += __shfl_xor(p3, 1, 64);
    p4 += __shfl_xor(p4, 1, 64); p5 += __shfl_xor(p5, 1, 64);
    p6 += __shfl_xor(p6, 1, 64); p7 += __shfl_xor(p7, 1, 64);
    p0 += __shfl_xor(p0, 2, 64); p1 += __shfl_xor(p1, 2, 64);
    p2 += __shfl_xor(p2, 2, 64); p3 += __shfl_xor(p3, 2, 64);
    p4 += __shfl_xor(p4, 2, 64); p5 += __shfl_xor(p5, 2, 64);
    p6 += __shfl_xor(p6, 2, 64); p7 += __shfl_xor(p7, 2, 64);
    p0 += __shfl_xor(p0, 4, 64); p1 += __shfl_xor(p1, 4, 64);
    p2 += __shfl_xor(p2, 4, 64); p3 += __shfl_xor(p3, 4, 64);
    p4 += __shfl_xor(p4, 4, 64); p5 += __shfl_xor(p5, 4, 64);
    p6 += __shfl_xor(p6, 4, 64); p7 += __shfl_xor(p7, 4, 64);
    int rem = hi - pos;   // scalar; >=1
    float e0 = __expf(p0);
    float e1 = (rem > 1) ? __expf(p1) : 0.f;
    float e2 = (rem > 2) ? __expf(p2) : 0.f;
    float e3 = (rem > 3) ? __expf(p3) : 0.f;
    float e4 = (rem > 4) ? __expf(p4) : 0.f;
    float e5 = (rem > 5) ? __expf(p5) : 0.f;
    float e6 = (rem > 6) ? __expf(p6) : 0.f;
    float e7 = (rem > 7) ? __expf(p7) : 0.f;
    acc0 += e0 * bf2f(v0.x) + e1 * bf2f(v1.x) + e2 * bf2f(v2.x) + e3 * bf2f(v3.x)
          + e4 * bf2f(v4.x) + e5 * bf2f(v5.x) + e6 * bf2f(v6.x) + e7 * bf2f(v7.x);
    acc1 += e0 * bf2f(v0.y) + e1 * bf2f(v1.y) + e2 * bf2f(v2.y) + e3 * bf2f(v3.y)
          + e4 * bf2f(v4.y) + e5 * bf2f(v5.y) + e6 * bf2f(v6.y) + e7 * bf2f(v7.y);
    ssum += ((e0 + e1) + (e2 + e3)) + ((e4 + e5) + (e6 + e7));
  }
  float inv = 1.f / (ssum + 1e-16f);
  float S0 = acc0 * inv, S1 = acc1 * inv;   // raw-V aggregate, d2 = 2el, 2el+1

  // ---- apply M_rel: out_j = sum_d2 S[d2] * M[h][d2][j], j = 2el, 2el+1 ----
  const float* M = rp.Mrel + (size_t)h * 256;
  float o0 = 0.f, o1 = 0.f;
  #pragma unroll
  for (int dd = 0; dd < 8; dd++) {
    float sa = __shfl(S0, grp + dd, 64);     // S_{2dd}
    float sb = __shfl(S1, grp + dd, 64);     // S_{2dd+1}
    o0 += sa * M[(2 * dd) * 16 + 2 * el] + sb * M[(2 * dd + 1) * 16 + 2 * el];
    o1 += sa * M[(2 * dd) * 16 + 2 * el + 1] + sb * M[(2 * dd + 1) * 16 + 2 * el + 1];
  }
  float* ap = rp.agg + (size_t)d * FDIM + 2 * lane;
  *(float2*)ap = make_float2(o0, o1);
}

// ---------------------------------------------------------------- scatter ---
__global__ __launch_bounds__(256) void scatter_out(const float* h0, const float* h1,
                                                   const float* h2, const int* ntype,
                                                   float* out, int NN) {
  int idx = blockIdx.x * 256 + threadIdx.x;
  if (idx >= NN * 32) return;
  int i = idx >> 5, c4 = idx & 31;
  int t = ntype[i];
  const float* hp = (t == 0) ? h0 : ((t == 1) ? h1 : h2);
  int local = i - t * NT_NODES;   // node_type_argmax is contiguous blocks per type
  ((float4*)out)[idx] = ((const float4*)hp)[(size_t)local * 32 + c4];
}

// ------------------------------------------------------------------- host ---
static const int ESRC[NRL] = {0, 0, 1, 0};
static const int EDST[NRL] = {0, 1, 0, 2};

extern "C" void kernel_launch(void* const* d_in, const int* in_sizes, int n_in,
                              void* d_out, int out_size, void* d_ws, size_t ws_size,
                              hipStream_t stream) {
  const float* x[3] = {(const float*)d_in[0], (const float*)d_in[1], (const float*)d_in[2]};
  const float* lin_w = (const float*)d_in[4];
  const float* lin_b = (const float*)d_in[5];
  const float* k_w   = (const float*)d_in[6];
  const float* k_b   = (const float*)d_in[7];
  const float* q_w   = (const float*)d_in[8];
  const float* q_b   = (const float*)d_in[9];
  const float* v_w   = (const float*)d_in[10];
  const float* v_b   = (const float*)d_in[11];
  const float* a_w   = (const float*)d_in[12];
  const float* a_b   = (const float*)d_in[13];
  const float* skip  = (const float*)d_in[14];
  const float* a_rel = (const float*)d_in[15];
  const float* m_rel = (const float*)d_in[16];
  const float* p_rel = (const float*)d_in[17];
  const int* edge_index = (const int*)d_in[18];
  const int* ntype   = (const int*)d_in[19];
  float* out = (float*)d_out;

  const size_t NF = (size_t)NT_NODES * FDIM;   // 3.84M elems per [N,128]
  float* p = (float*)d_ws;
  auto alloc = [&](size_t n) { float* r = p; p += n; return r; };
  float* bufA = alloc(3 * NF);                    // h (ping)
  float* bufB = alloc(3 * NF);                    // h (pong); bf16 Q aliases alt
  float* agg  = alloc(3 * NF);                    // rels 0,1,3 -> dst types 0,1,2
  float* aggX = alloc(NF);                        // rel 2 -> dst type 0 (summed in GEMM)
  u16* kbf0 = (u16*)alloc(NF / 2);                // bf16 K, src type 0
  u16* vbf0 = (u16*)alloc(NF / 2);                // bf16 V, src type 0
  u16* kbf1 = (u16*)alloc(NF / 2);                // bf16 K, src type 1
  u16* vbf1 = (u16*)alloc(NF / 2);                // bf16 V, src type 1
  int* counts  = (int*)(p);                       // [4][N]
  int* cursor  = counts + NRL * NT_NODES;         // [4][N]
  int* offsets = cursor + NRL * NT_NODES;         // [4][N+1]
  int* aux     = offsets + NRL * (NT_NODES + 1);  // [4][118]
  int* auxe    = aux + NRL * SCAN_BLOCKS;         // [4][118]
  int* csr_src = auxe + NRL * SCAN_BLOCKS;        // [4][E] + 8 slack

  const int gemm_gx = (NT_NODES + 63) / 64;   // 469

  // ---- CSR build (edge_index fixed within a call; reused by both layers) ----
  hipMemsetAsync(counts, 0, NRL * NT_NODES * sizeof(int), stream);
  csr_hist<<<dim3((NRL * NE_EDGES + 255) / 256), 256, 0, stream>>>(edge_index, counts);
  scan_block<<<dim3(SCAN_BLOCKS, NRL), 256, 0, stream>>>(counts, offsets, aux);
  scan_aux<<<dim3(NRL), 128, 0, stream>>>(aux, auxe, offsets);
  scan_add<<<dim3(SCAN_BLOCKS, NRL), 256, 0, stream>>>(auxe, offsets, cursor);
  csr_scatter<<<dim3((NRL * NE_EDGES + 255) / 256), 256, 0, stream>>>(edge_index, cursor, csr_src);
  csr_pad<<<dim3(1), 64, 0, stream>>>(csr_src + (size_t)NRL * NE_EDGES);

  // input projection: hs[t] = relu(x_t @ lin_w[t] + lin_b[t])
  {
    GemmBatch gb{};
    for (int t = 0; t < 3; t++) {
      gb.t[t].A = x[t];
      gb.t[t].W = lin_w + (size_t)t * FDIM * FDIM;
      gb.t[t].bias = lin_b + (size_t)t * FDIM;
      gb.t[t].C = bufA + (size_t)t * NF;
    }
    gemm_f32<0, 0, 1, 0><<<dim3(gemm_gx, 1, 3), 256, 0, stream>>>(gb, NT_NODES);
  }

  float* cur = bufA;   // current h (fp32)
  float* alt = bufB;   // bf16 Q scratch now, fp32 next-h later
  for (int l = 0; l < NLY; l++) {
    u16* qbf = (u16*)alt;

    // Q for all 3 types + raw K/V for src types 0 and 1 — all bf16, one launch
    {
      GemmBatch gb{};
      for (int t = 0; t < 3; t++) {
        gb.t[t].A = cur + (size_t)t * NF;
        gb.t[t].W = q_w + (size_t)(l * NTY + t) * FDIM * FDIM;
        gb.t[t].bias = q_b + (size_t)(l * NTY + t) * FDIM;
        gb.t[t].C = (float*)(qbf + (size_t)t * NF);
      }
      gb.t[3].A = cur;                                   // src type 0
      gb.t[3].W = k_w + (size_t)(l * NTY + 0) * FDIM * FDIM;
      gb.t[3].bias = k_b + (size_t)(l * NTY + 0) * FDIM;
      gb.t[3].C = (float*)kbf0;
      gb.t[4].A = cur;
      gb.t[4].W = v_w + (size_t)(l * NTY + 0) * FDIM * FDIM;
      gb.t[4].bias = v_b + (size_t)(l * NTY + 0) * FDIM;
      gb.t[4].C = (float*)vbf0;
      gb.t[5].A = cur + NF;                              // src type 1
      gb.t[5].W = k_w + (size_t)(l * NTY + 1) * FDIM * FDIM;
      gb.t[5].bias = k_b + (size_t)(l * NTY + 1) * FDIM;
      gb.t[5].C = (float*)kbf1;
      gb.t[6].A = cur + NF;
      gb.t[6].W = v_w + (size_t)(l * NTY + 1) * FDIM * FDIM;
      gb.t[6].bias = v_b + (size_t)(l * NTY + 1) * FDIM;
      gb.t[6].C = (float*)vbf1;
      gemm_f32<0, 0, 0, 1><<<dim3(gemm_gx, 1, 7), 256, 0, stream>>>(gb, NT_NODES);
    }

    // attention: ALL 4 relations in one launch. rel2 writes aggX (no dependency)
    {
      AttnBatch ab{};
      for (int r = 0; r < NRL; r++) {
        int dt = EDST[r];
        ab.r[r].csr_src = csr_src + (size_t)r * NE_EDGES;
        ab.r[r].off  = offsets + (size_t)r * (NT_NODES + 1);
        ab.r[r].q    = qbf + (size_t)dt * NF;
        ab.r[r].kraw = (ESRC[r] == 0) ? kbf0 : kbf1;
        ab.r[r].vraw = (ESRC[r] == 0) ? vbf0 : vbf1;
        ab.r[r].Arel = a_rel + (size_t)(l * NRL + r) * NH * HD * HD;
        ab.r[r].Mrel = m_rel + (size_t)(l * NRL + r) * NH * HD * HD;
        ab.r[r].prel = p_rel + (size_t)(l * NRL + r) * NH;
        ab.r[r].agg  = (r == 2) ? aggX : (agg + (size_t)dt * NF);
      }
      attn_fused<<<dim3((NT_NODES + 3) / 4, NRL), 256, 0, stream>>>(ab);
    }

    // out: hs_new[t] = a_s*(gelu(agg[t] [+aggX]) @ a_w + a_b) + (1-a_s)*hs[t]
    {
      GemmBatch gb{};
      for (int t = 0; t < 3; t++) {
        gb.t[t].A = agg + (size_t)t * NF;
        gb.t[t].A2 = (t == 0) ? aggX : nullptr;
        gb.t[t].W = a_w + (size_t)(l * NTY + t) * FDIM * FDIM;
        gb.t[t].bias = a_b + (size_t)(l * NTY + t) * FDIM;
        gb.t[t].C = alt + (size_t)t * NF;
        gb.t[t].oldh = cur + (size_t)t * NF;
        gb.t[t].skipp = skip + (size_t)(l * NTY + t);
      }
      gemm_f32<1, 1, 0, 0><<<dim3(gemm_gx, 1, 3), 256, 0, stream>>>(gb, NT_NODES);
    }
    float* tmp = cur; cur = alt; alt = tmp;
  }

  // scatter per-type rows back to global node order
  const int NN = 3 * NT_NODES;
  scatter_out<<<dim3((NN * 32 + 255) / 256), 256, 0, stream>>>(
      cur, cur + NF, cur + 2 * NF, ntype, out, NN);
}

// Round 9
// 689.189 us; speedup vs baseline: 1.6599x; 1.1935x over previous
//
#include <hip/hip_runtime.h>
#include <math.h>

#define NT_NODES 30000
#define NE_EDGES 200000
#define NTY 3
#define NRL 4
#define NLY 2
#define NH 8
#define HD 16
#define FDIM 128
#define SCAN_BLOCKS 118   // ceil(30000/256)

typedef unsigned short u16;
typedef unsigned int u32;
typedef __attribute__((ext_vector_type(8))) short bf16x8;
typedef __attribute__((ext_vector_type(4))) float f32x4;

__device__ __forceinline__ float bf2f(u16 u) {
  return __uint_as_float(((u32)u) << 16);
}
__device__ __forceinline__ u16 f2bf(float f) {   // RNE
  u32 u = __float_as_uint(f);
  return (u16)((u + 0x7FFFu + ((u >> 16) & 1u)) >> 16);
}

__device__ __forceinline__ float gelu_f(float x) {
  return 0.5f * x * (1.f + erff(x * 0.7071067811865475f));
}

// -------------------------------------------------- weight prep (bf16 W^T) --
struct WtBatch { const float* w[14]; };
__global__ __launch_bounds__(256) void wt_prep(WtBatch wb, u16* wt) {
  const float* w = wb.w[blockIdx.x];
  u16* o = wt + (size_t)blockIdx.x * FDIM * FDIM;
  // output-major: coalesced 2B writes, scattered 4B reads (L2-friendly)
  for (int i = threadIdx.x; i < FDIM * FDIM; i += 256) {
    int n = i >> 7, k = i & 127;            // o[n][k] = w[k][n]
    o[i] = f2bf(w[(size_t)k * FDIM + n]);
  }
}

// ------------------------------------------------------- MFMA bf16 GEMM -----
// C_bf16[M,128] = A_f32[M,128] @ W[128,128] + bias.  WT is bf16 W^T [n][k].
// Block: 256 thr (4 waves), tile 64 rows; wave w -> cols 32w..32w+31.
// LDS XOR-swizzle on 16B granules: granule k8 stored at k8 ^ (row&7).
struct GemmTaskB { const float* A; const u16* WT; const float* bias; u16* C; int ldc; };
struct GemmBatchB { GemmTaskB t[7]; };

__global__ __launch_bounds__(256) void gemm_mfma(GemmBatchB gb, int M) {
  const GemmTaskB tk = gb.t[blockIdx.z];
  const int tid = threadIdx.x;
  const int wv = tid >> 6;
  const int lane = tid & 63;
  const int row0 = blockIdx.x * 64;

  __shared__ u16 As[64 * 128];    // [row][k], swizzled granules
  __shared__ u16 Bt[128 * 128];   // [n][k],  swizzled granules

  // stage A (fp32 -> bf16): granule g = (row, k8); 4 per thread
  #pragma unroll
  for (int i = 0; i < 4; i++) {
    int g = tid + 256 * i;              // 0..1023
    int r = g >> 4, k8 = g & 15;
    int grow = row0 + r;
    float4 va = make_float4(0.f, 0.f, 0.f, 0.f), vb = va;
    if (grow < M) {
      const float* ap = tk.A + (size_t)grow * FDIM + k8 * 8;
      va = *(const float4*)ap;
      vb = *(const float4*)(ap + 4);
    }
    u32 w0 = (u32)f2bf(va.x) | ((u32)f2bf(va.y) << 16);
    u32 w1 = (u32)f2bf(va.z) | ((u32)f2bf(va.w) << 16);
    u32 w2 = (u32)f2bf(vb.x) | ((u32)f2bf(vb.y) << 16);
    u32 w3 = (u32)f2bf(vb.z) | ((u32)f2bf(vb.w) << 16);
    u32* dst = (u32*)(As + r * 128 + ((k8 ^ (r & 7)) * 8));
    dst[0] = w0; dst[1] = w1; dst[2] = w2; dst[3] = w3;
  }
  // stage B^T (bf16 -> bf16): 8 granules per thread
  #pragma unroll
  for (int i = 0; i < 8; i++) {
    int g = tid + 256 * i;              // 0..2047
    int n = g >> 4, k8 = g & 15;
    uint4 v = *(const uint4*)(tk.WT + (size_t)n * FDIM + k8 * 8);
    *(uint4*)(Bt + n * 128 + ((k8 ^ (n & 7)) * 8)) = v;
  }
  __syncthreads();

  f32x4 acc[4][2] = {};
  const int rsel = lane & 15, ksel = lane >> 4;   // ksel 0..3
  #pragma unroll
  for (int ks = 0; ks < 4; ks++) {
    int kg = ks * 4 + ksel;                        // K granule
    bf16x8 af[4], bfr[2];
    #pragma unroll
    for (int i = 0; i < 4; i++) {
      int r = 16 * i + rsel;
      af[i] = *(const bf16x8*)(As + r * 128 + ((kg ^ (r & 7)) * 8));
    }
    #pragma unroll
    for (int j = 0; j < 2; j++) {
      int n = 32 * wv + 16 * j + rsel;
      bfr[j] = *(const bf16x8*)(Bt + n * 128 + ((kg ^ (n & 7)) * 8));
    }
    #pragma unroll
    for (int i = 0; i < 4; i++)
      #pragma unroll
      for (int j = 0; j < 2; j++)
        acc[i][j] = __builtin_amdgcn_mfma_f32_16x16x32_bf16(af[i], bfr[j], acc[i][j], 0, 0, 0);
  }

  // epilogue: C/D layout col=lane&15, row=(lane>>4)*4+rr
  const int ldc = tk.ldc;
  float bj[2];
  #pragma unroll
  for (int j = 0; j < 2; j++) bj[j] = tk.bias[32 * wv + 16 * j + rsel];
  #pragma unroll
  for (int i = 0; i < 4; i++) {
    #pragma unroll
    for (int rr = 0; rr < 4; rr++) {
      int grow = row0 + 16 * i + (lane >> 4) * 4 + rr;
      if (grow >= M) continue;
      #pragma unroll
      for (int j = 0; j < 2; j++) {
        int col = 32 * wv + 16 * j + rsel;
        tk.C[(size_t)grow * ldc + col] = f2bf(acc[i][j][rr] + bj[j]);
      }
    }
  }
}

// ---------------------------------------------------------------- f32 GEMM --
// kept for in-proj (RELU) and out (GELU_A + EPI_SKIP) — numerically safest.
struct GemmTask {
  const float* A; const float* W; const float* bias; float* C;
  const float* oldh; const float* skipp;
  const float* A2;
};
struct GemmBatch { GemmTask t[3]; };

template<int GELU_A, int EPI_SKIP, int RELU>
__global__ __launch_bounds__(256) void gemm_f32(GemmBatch gb, int M) {
  const GemmTask tk = gb.t[blockIdx.z];
  const int tid = threadIdx.x;
  const int tx2 = tid & 15;
  const int ty2 = tid >> 4;
  const int row0 = blockIdx.x * 64;

  __shared__ float AsT[32][64];
  __shared__ float Bs[32][128];

  float acc[4][8];
  #pragma unroll
  for (int i = 0; i < 4; i++)
    #pragma unroll
    for (int j = 0; j < 8; j++) acc[i][j] = 0.f;

  for (int k0 = 0; k0 < FDIM; k0 += 32) {
    #pragma unroll
    for (int i = 0; i < 2; i++) {
      int slot = tid + 256 * i;
      int r = slot >> 3, f4 = slot & 7;
      int grow = row0 + r;
      float4 v = make_float4(0.f, 0.f, 0.f, 0.f);
      if (grow < M) {
        v = *(const float4*)(tk.A + (size_t)grow * FDIM + k0 + f4 * 4);
        if (GELU_A && tk.A2) {
          float4 v2 = *(const float4*)(tk.A2 + (size_t)grow * FDIM + k0 + f4 * 4);
          v.x += v2.x; v.y += v2.y; v.z += v2.z; v.w += v2.w;
        }
      }
      if (GELU_A) { v.x = gelu_f(v.x); v.y = gelu_f(v.y); v.z = gelu_f(v.z); v.w = gelu_f(v.w); }
      AsT[f4 * 4 + 0][r] = v.x;
      AsT[f4 * 4 + 1][r] = v.y;
      AsT[f4 * 4 + 2][r] = v.z;
      AsT[f4 * 4 + 3][r] = v.w;
    }
    #pragma unroll
    for (int i = 0; i < 4; i++) {
      int slot = tid + 256 * i;
      int r = slot >> 5, f4 = slot & 31;
      float4 v = *(const float4*)(tk.W + (size_t)(k0 + r) * FDIM + f4 * 4);
      *(float4*)(&Bs[r][f4 * 4]) = v;
    }
    __syncthreads();
    #pragma unroll
    for (int kk = 0; kk < 32; kk++) {
      float4 a4 = *(const float4*)(&AsT[kk][ty2 * 4]);
      float4 b0 = *(const float4*)(&Bs[kk][tx2 * 8]);
      float4 b1 = *(const float4*)(&Bs[kk][tx2 * 8 + 4]);
      const float av[4] = {a4.x, a4.y, a4.z, a4.w};
      #pragma unroll
      for (int i = 0; i < 4; i++) {
        acc[i][0] += av[i] * b0.x; acc[i][1] += av[i] * b0.y;
        acc[i][2] += av[i] * b0.z; acc[i][3] += av[i] * b0.w;
        acc[i][4] += av[i] * b1.x; acc[i][5] += av[i] * b1.y;
        acc[i][6] += av[i] * b1.z; acc[i][7] += av[i] * b1.w;
      }
    }
    __syncthreads();
  }

  float4 bias0 = *(const float4*)(tk.bias + tx2 * 8);
  float4 bias1 = *(const float4*)(tk.bias + tx2 * 8 + 4);
  float a_s = 0.f;
  if (EPI_SKIP) a_s = 1.f / (1.f + expf(-tk.skipp[0]));

  #pragma unroll
  for (int i = 0; i < 4; i++) {
    int grow = row0 + ty2 * 4 + i;
    if (grow >= M) continue;
    float o[8];
    o[0] = acc[i][0] + bias0.x; o[1] = acc[i][1] + bias0.y;
    o[2] = acc[i][2] + bias0.z; o[3] = acc[i][3] + bias0.w;
    o[4] = acc[i][4] + bias1.x; o[5] = acc[i][5] + bias1.y;
    o[6] = acc[i][6] + bias1.z; o[7] = acc[i][7] + bias1.w;
    if (RELU) {
      #pragma unroll
      for (int j = 0; j < 8; j++) o[j] = fmaxf(o[j], 0.f);
    }
    if (EPI_SKIP) {
      const float* hp = tk.oldh + (size_t)grow * FDIM + tx2 * 8;
      float4 h0 = *(const float4*)(hp);
      float4 h1 = *(const float4*)(hp + 4);
      float b_s = 1.f - a_s;
      o[0] = a_s * o[0] + b_s * h0.x; o[1] = a_s * o[1] + b_s * h0.y;
      o[2] = a_s * o[2] + b_s * h0.z; o[3] = a_s * o[3] + b_s * h0.w;
      o[4] = a_s * o[4] + b_s * h1.x; o[5] = a_s * o[5] + b_s * h1.y;
      o[6] = a_s * o[6] + b_s * h1.z; o[7] = a_s * o[7] + b_s * h1.w;
    }
    float* cp = tk.C + (size_t)grow * FDIM + tx2 * 8;
    *(float4*)cp = make_float4(o[0], o[1], o[2], o[3]);
    *(float4*)(cp + 4) = make_float4(o[4], o[5], o[6], o[7]);
  }
}

// ------------------------------------------------------------- CSR build ----
__global__ __launch_bounds__(256) void csr_hist(const int* __restrict__ edge_index,
                                                int* __restrict__ counts) {
  int idx = blockIdx.x * 256 + threadIdx.x;
  if (idx >= NRL * NE_EDGES) return;
  int r = idx / NE_EDGES, e = idx - r * NE_EDGES;
  int d = edge_index[(size_t)(r * 2 + 1) * NE_EDGES + e];
  atomicAdd(&counts[r * NT_NODES + d], 1);
}

__global__ __launch_bounds__(256) void scan_block(const int* __restrict__ counts,
                                                  int* __restrict__ off,
                                                  int* __restrict__ aux) {
  int r = blockIdx.y, b = blockIdx.x, t = threadIdx.x;
  int i = b * 256 + t;
  int v = (i < NT_NODES) ? counts[r * NT_NODES + i] : 0;
  __shared__ int lds[256];
  lds[t] = v;
  __syncthreads();
  #pragma unroll
  for (int dlt = 1; dlt < 256; dlt <<= 1) {
    int x = (t >= dlt) ? lds[t - dlt] : 0;
    __syncthreads();
    lds[t] += x;
    __syncthreads();
  }
  if (i < NT_NODES) off[(size_t)r * (NT_NODES + 1) + i] = lds[t] - v;
  if (t == 255) aux[r * SCAN_BLOCKS + b] = lds[255];
}

__global__ __launch_bounds__(128) void scan_aux(const int* __restrict__ aux,
                                                int* __restrict__ auxe,
                                                int* __restrict__ off) {
  int r = blockIdx.x, t = threadIdx.x;
  __shared__ int lds[128];
  int v = (t < SCAN_BLOCKS) ? aux[r * SCAN_BLOCKS + t] : 0;
  lds[t] = v;
  __syncthreads();
  #pragma unroll
  for (int dlt = 1; dlt < 128; dlt <<= 1) {
    int x = (t >= dlt) ? lds[t - dlt] : 0;
    __syncthreads();
    lds[t] += x;
    __syncthreads();
  }
  if (t < SCAN_BLOCKS) auxe[r * SCAN_BLOCKS + t] = lds[t] - v;
  if (t == 127) off[(size_t)r * (NT_NODES + 1) + NT_NODES] = lds[127];
}

__global__ __launch_bounds__(256) void scan_add(const int* __restrict__ auxe,
                                                int* __restrict__ off,
                                                int* __restrict__ cursor) {
  int r = blockIdx.y, b = blockIdx.x, t = threadIdx.x;
  int i = b * 256 + t;
  if (i >= NT_NODES) return;
  int val = off[(size_t)r * (NT_NODES + 1) + i] + auxe[r * SCAN_BLOCKS + b];
  off[(size_t)r * (NT_NODES + 1) + i] = val;
  cursor[r * NT_NODES + i] = val;
}

__global__ __launch_bounds__(256) void csr_scatter(const int* __restrict__ edge_index,
                                                   int* __restrict__ cursor,
                                                   int* __restrict__ csr_src) {
  int idx = blockIdx.x * 256 + threadIdx.x;
  if (idx >= NRL * NE_EDGES) return;
  int r = idx / NE_EDGES, e = idx - r * NE_EDGES;
  int s = edge_index[(size_t)(r * 2 + 0) * NE_EDGES + e];
  int d = edge_index[(size_t)(r * 2 + 1) * NE_EDGES + e];
  int pos = atomicAdd(&cursor[r * NT_NODES + d], 1);
  csr_src[(size_t)r * NE_EDGES + pos] = s;
}

__global__ void csr_pad(int* __restrict__ pad) {
  if (threadIdx.x < 8) pad[threadIdx.x] = 0;
}

// ---------------------------------------------------- fused attention -------
// One wave per dst node. KV interleaved table [N][256] bf16 (K: 0..127, V:
// 128..255). 8-edge batches; dot reduction via transposed pair-reduce
// butterfly (7 shfl, lane el<8 in each head group ends holding edge el's
// logit), 1 exp/lane, 8 broadcast shfls for the V accumulation.
struct AttnRel {
  const int* csr_src; const int* off;
  const u16* q;        // bf16 Q of dst type [N,128]
  const u16* kv;       // bf16 interleaved K|V of src type [N,256]
  const float* Arel;   // [8][16][16]
  const float* Mrel;   // [8][16][16]
  const float* prel;   // [8]
  float* agg;          // output [N,128] (overwritten)
};
struct AttnBatch { AttnRel r[4]; };

__global__ __launch_bounds__(256) void attn_fused(AttnBatch ab) {
  const AttnRel rp = ab.r[blockIdx.y];
  const int wave = threadIdx.x >> 6;
  const int lane = threadIdx.x & 63;
  const int d = blockIdx.x * 4 + wave;
  if (d >= NT_NODES) return;
  const int h = lane >> 3;         // head 0..7
  const int el = lane & 7;         // pair index within head (channels 2el,2el+1)
  const int grp = h << 3;          // first lane of head group

  // ---- q' = (A_h @ q_h) * p_h/4 via shfl within 8-lane head groups ----
  ushort2 qu = ((const ushort2*)rp.q)[(size_t)d * 64 + lane];
  float q0 = bf2f(qu.x), q1 = bf2f(qu.y);
  const float* A = rp.Arel + (size_t)h * 256;
  float qp0 = 0.f, qp1 = 0.f;
  #pragma unroll
  for (int ee = 0; ee < 8; ee++) {
    float qa = __shfl(q0, grp + ee, 64);
    float qb = __shfl(q1, grp + ee, 64);
    qp0 += A[(2 * el) * 16 + 2 * ee] * qa + A[(2 * el) * 16 + 2 * ee + 1] * qb;
    qp1 += A[(2 * el + 1) * 16 + 2 * ee] * qa + A[(2 * el + 1) * 16 + 2 * ee + 1] * qb;
  }
  float sc = rp.prel[h] * 0.25f;
  qp0 *= sc; qp1 *= sc;

  const ushort2* KV = (const ushort2*)rp.kv;   // [N][128] ushort2 units
  const int* __restrict__ cs = rp.csr_src;
  int lo = rp.off[d], hi = rp.off[d + 1];
  lo = __builtin_amdgcn_readfirstlane(lo);
  hi = __builtin_amdgcn_readfirstlane(hi);
  float acc0 = 0.f, acc1 = 0.f, ssum = 0.f;
  for (int pos = lo; pos < hi; pos += 8) {
    int s0 = cs[pos + 0], s1 = cs[pos + 1], s2 = cs[pos + 2], s3 = cs[pos + 3];
    int s4 = cs[pos + 4], s5 = cs[pos + 5], s6 = cs[pos + 6], s7 = cs[pos + 7];
    ushort2 k0 = KV[(size_t)s0 * 128 + lane], k1 = KV[(size_t)s1 * 128 + lane];
    ushort2 k2 = KV[(size_t)s2 * 128 + lane], k3 = KV[(size_t)s3 * 128 + lane];
    ushort2 k4 = KV[(size_t)s4 * 128 + lane], k5 = KV[(size_t)s5 * 128 + lane];
    ushort2 k6 = KV[(size_t)s6 * 128 + lane], k7 = KV[(size_t)s7 * 128 + lane];
    ushort2 v0 = KV[(size_t)s0 * 128 + 64 + lane], v1 = KV[(size_t)s1 * 128 + 64 + lane];
    ushort2 v2 = KV[(size_t)s2 * 128 + 64 + lane], v3 = KV[(size_t)s3 * 128 + 64 + lane];
    ushort2 v4 = KV[(size_t)s4 * 128 + 64 + lane], v5 = KV[(size_t)s5 * 128 + 64 + lane];
    ushort2 v6 = KV[(size_t)s6 * 128 + 64 + lane], v7 = KV[(size_t)s7 * 128 + 64 + lane];
    float p0 = qp0 * bf2f(k0.x) + qp1 * bf2f(k0.y);
    float p1 = qp0 * bf2f(k1.x) + qp1 * bf2f(k1.y);
    float p2 = qp0 * bf2f(k2.x) + qp1 * bf2f(k2.y);
    float p3 = qp0 * bf2f(k3.x) + qp1 * bf2f(k3.y);
    float p4 = qp0 * bf2f(k4.x) + qp1 * bf2f(k4.y);
    float p5 = qp0 * bf2f(k5.x) + qp1 * bf2f(k5.y);
    float p6 = qp0 * bf2f(k6.x) + qp1 * bf2f(k6.y);
    float p7 = qp0 * bf2f(k7.x) + qp1 * bf2f(k7.y);
    // stage 1 (mask 1): 4 value-pairs, 4 shfls
    float s01 = (el & 1) ? p0 : p1, c01 = (el & 1) ? p1 : p0;
    float s23 = (el & 1) ? p2 : p3, c23 = (el & 1) ? p3 : p2;
    float s45 = (el & 1) ? p4 : p5, c45 = (el & 1) ? p5 : p4;
    float s67 = (el & 1) ? p6 : p7, c67 = (el & 1) ? p7 : p6;
    float r01 = c01 + __shfl_xor(s01, 1, 64);
    float r23 = c23 + __shfl_xor(s23, 1, 64);
    float r45 = c45 + __shfl_xor(s45, 1, 64);
    float r67 = c67 + __shfl_xor(s67, 1, 64);
    // stage 2 (mask 2): 2 shfls
    float sA = (el & 2) ? r01 : r23, cA = (el & 2) ? r23 : r01;
    float sB = (el & 2) ? r45 : r67, cB = (el & 2) ? r67 : r45;
    float rA = cA + __shfl_xor(sA, 2, 64);
    float rB = cB + __shfl_xor(sB, 2, 64);
    // stage 3 (mask 4): 1 shfl -> lane el holds logit of edge el
    float sC = (el & 4) ? rA : rB, cC = (el & 4) ? rB : rA;
    float rF = cC + __shfl_xor(sC, 4, 64);
    int rem = hi - pos;   // scalar
    float e = (el < rem) ? __expf(rF) : 0.f;
    float e0 = __shfl(e, grp + 0, 64), e1 = __shfl(e, grp + 1, 64);
    float e2 = __shfl(e, grp + 2, 64), e3 = __shfl(e, grp + 3, 64);
    float e4 = __shfl(e, grp + 4, 64), e5 = __shfl(e, grp + 5, 64);
    float e6 = __shfl(e, grp + 6, 64), e7 = __shfl(e, grp + 7, 64);
    acc0 += e0 * bf2f(v0.x) + e1 * bf2f(v1.x) + e2 * bf2f(v2.x) + e3 * bf2f(v3.x)
          + e4 * bf2f(v4.x) + e5 * bf2f(v5.x) + e6 * bf2f(v6.x) + e7 * bf2f(v7.x);
    acc1 += e0 * bf2f(v0.y) + e1 * bf2f(v1.y) + e2 * bf2f(v2.y) + e3 * bf2f(v3.y)
          + e4 * bf2f(v4.y) + e5 * bf2f(v5.y) + e6 * bf2f(v6.y) + e7 * bf2f(v7.y);
    ssum += ((e0 + e1) + (e2 + e3)) + ((e4 + e5) + (e6 + e7));
  }
  float inv = 1.f / (ssum + 1e-16f);
  float S0 = acc0 * inv, S1 = acc1 * inv;

  // ---- apply M_rel: out_j = sum_d2 S[d2] * M[h][d2][j] ----
  const float* M = rp.Mrel + (size_t)h * 256;
  float o0 = 0.f, o1 = 0.f;
  #pragma unroll
  for (int dd = 0; dd < 8; dd++) {
    float sa = __shfl(S0, grp + dd, 64);
    float sb = __shfl(S1, grp + dd, 64);
    o0 += sa * M[(2 * dd) * 16 + 2 * el] + sb * M[(2 * dd + 1) * 16 + 2 * el];
    o1 += sa * M[(2 * dd) * 16 + 2 * el + 1] + sb * M[(2 * dd + 1) * 16 + 2 * el + 1];
  }
  float* ap = rp.agg + (size_t)d * FDIM + 2 * lane;
  *(float2*)ap = make_float2(o0, o1);
}

// ---------------------------------------------------------------- scatter ---
__global__ __launch_bounds__(256) void scatter_out(const float* h0, const float* h1,
                                                   const float* h2, const int* ntype,
                                                   float* out, int NN) {
  int idx = blockIdx.x * 256 + threadIdx.x;
  if (idx >= NN * 32) return;
  int i = idx >> 5, c4 = idx & 31;
  int t = ntype[i];
  const float* hp = (t == 0) ? h0 : ((t == 1) ? h1 : h2);
  int local = i - t * NT_NODES;
  ((float4*)out)[idx] = ((const float4*)hp)[(size_t)local * 32 + c4];
}

// ------------------------------------------------------------------- host ---
static const int ESRC[NRL] = {0, 0, 1, 0};
static const int EDST[NRL] = {0, 1, 0, 2};

extern "C" void kernel_launch(void* const* d_in, const int* in_sizes, int n_in,
                              void* d_out, int out_size, void* d_ws, size_t ws_size,
                              hipStream_t stream) {
  const float* x[3] = {(const float*)d_in[0], (const float*)d_in[1], (const float*)d_in[2]};
  const float* lin_w = (const float*)d_in[4];
  const float* lin_b = (const float*)d_in[5];
  const float* k_w   = (const float*)d_in[6];
  const float* k_b   = (const float*)d_in[7];
  const float* q_w   = (const float*)d_in[8];
  const float* q_b   = (const float*)d_in[9];
  const float* v_w   = (const float*)d_in[10];
  const float* v_b   = (const float*)d_in[11];
  const float* a_w   = (const float*)d_in[12];
  const float* a_b   = (const float*)d_in[13];
  const float* skip  = (const float*)d_in[14];
  const float* a_rel = (const float*)d_in[15];
  const float* m_rel = (const float*)d_in[16];
  const float* p_rel = (const float*)d_in[17];
  const int* edge_index = (const int*)d_in[18];
  const int* ntype   = (const int*)d_in[19];
  float* out = (float*)d_out;

  const size_t NF = (size_t)NT_NODES * FDIM;
  float* p = (float*)d_ws;
  auto alloc = [&](size_t n) { float* r = p; p += n; return r; };
  float* bufA = alloc(3 * NF);                    // h (ping)
  float* bufB = alloc(3 * NF);                    // h (pong); bf16 Q aliases
  float* agg  = alloc(3 * NF);                    // rels 0,1,3
  float* aggX = alloc(NF);                        // rel 2 (summed in out-GEMM)
  u16* kv0 = (u16*)alloc(NF);                     // interleaved K|V, src type 0 [N][256]
  u16* kv1 = (u16*)alloc(NF);                     // interleaved K|V, src type 1
  u16* wt  = (u16*)alloc(14 * FDIM * FDIM / 2);   // 14 bf16 W^T matrices
  int* counts  = (int*)(p);
  int* cursor  = counts + NRL * NT_NODES;
  int* offsets = cursor + NRL * NT_NODES;
  int* aux     = offsets + NRL * (NT_NODES + 1);
  int* auxe    = aux + NRL * SCAN_BLOCKS;
  int* csr_src = auxe + NRL * SCAN_BLOCKS;        // [4][E] + 8 slack

  const int gemm_gx = (NT_NODES + 63) / 64;   // 469

  // ---- weight prep: bf16 W^T for the 14 QKV matrices (both layers) ----
  {
    WtBatch wb{};
    for (int l = 0; l < NLY; l++) {
      for (int t = 0; t < 3; t++)
        wb.w[l * 7 + t] = q_w + (size_t)(l * NTY + t) * FDIM * FDIM;
      wb.w[l * 7 + 3] = k_w + (size_t)(l * NTY + 0) * FDIM * FDIM;
      wb.w[l * 7 + 4] = v_w + (size_t)(l * NTY + 0) * FDIM * FDIM;
      wb.w[l * 7 + 5] = k_w + (size_t)(l * NTY + 1) * FDIM * FDIM;
      wb.w[l * 7 + 6] = v_w + (size_t)(l * NTY + 1) * FDIM * FDIM;
    }
    wt_prep<<<dim3(14), 256, 0, stream>>>(wb, wt);
  }

  // ---- CSR build ----
  hipMemsetAsync(counts, 0, NRL * NT_NODES * sizeof(int), stream);
  csr_hist<<<dim3((NRL * NE_EDGES + 255) / 256), 256, 0, stream>>>(edge_index, counts);
  scan_block<<<dim3(SCAN_BLOCKS, NRL), 256, 0, stream>>>(counts, offsets, aux);
  scan_aux<<<dim3(NRL), 128, 0, stream>>>(aux, auxe, offsets);
  scan_add<<<dim3(SCAN_BLOCKS, NRL), 256, 0, stream>>>(auxe, offsets, cursor);
  csr_scatter<<<dim3((NRL * NE_EDGES + 255) / 256), 256, 0, stream>>>(edge_index, cursor, csr_src);
  csr_pad<<<dim3(1), 64, 0, stream>>>(csr_src + (size_t)NRL * NE_EDGES);

  // input projection: hs[t] = relu(x_t @ lin_w[t] + lin_b[t])  (fp32)
  {
    GemmBatch gb{};
    for (int t = 0; t < 3; t++) {
      gb.t[t].A = x[t];
      gb.t[t].W = lin_w + (size_t)t * FDIM * FDIM;
      gb.t[t].bias = lin_b + (size_t)t * FDIM;
      gb.t[t].C = bufA + (size_t)t * NF;
    }
    gemm_f32<0, 0, 1><<<dim3(gemm_gx, 1, 3), 256, 0, stream>>>(gb, NT_NODES);
  }

  float* cur = bufA;
  float* alt = bufB;
  for (int l = 0; l < NLY; l++) {
    u16* qbf = (u16*)alt;

    // Q (3 types) + K/V (src types 0,1 interleaved) — MFMA bf16, one launch
    {
      GemmBatchB gb{};
      for (int t = 0; t < 3; t++) {
        gb.t[t].A = cur + (size_t)t * NF;
        gb.t[t].WT = wt + (size_t)(l * 7 + t) * FDIM * FDIM;
        gb.t[t].bias = q_b + (size_t)(l * NTY + t) * FDIM;
        gb.t[t].C = qbf + (size_t)t * NF;
        gb.t[t].ldc = FDIM;
      }
      gb.t[3].A = cur;  gb.t[3].WT = wt + (size_t)(l * 7 + 3) * FDIM * FDIM;
      gb.t[3].bias = k_b + (size_t)(l * NTY + 0) * FDIM;
      gb.t[3].C = kv0;        gb.t[3].ldc = 256;
      gb.t[4].A = cur;  gb.t[4].WT = wt + (size_t)(l * 7 + 4) * FDIM * FDIM;
      gb.t[4].bias = v_b + (size_t)(l * NTY + 0) * FDIM;
      gb.t[4].C = kv0 + 128;  gb.t[4].ldc = 256;
      gb.t[5].A = cur + NF;  gb.t[5].WT = wt + (size_t)(l * 7 + 5) * FDIM * FDIM;
      gb.t[5].bias = k_b + (size_t)(l * NTY + 1) * FDIM;
      gb.t[5].C = kv1;        gb.t[5].ldc = 256;
      gb.t[6].A = cur + NF;  gb.t[6].WT = wt + (size_t)(l * 7 + 6) * FDIM * FDIM;
      gb.t[6].bias = v_b + (size_t)(l * NTY + 1) * FDIM;
      gb.t[6].C = kv1 + 128;  gb.t[6].ldc = 256;
      gemm_mfma<<<dim3(gemm_gx, 1, 7), 256, 0, stream>>>(gb, NT_NODES);
    }

    // attention: all 4 relations, one launch
    {
      AttnBatch ab{};
      for (int r = 0; r < NRL; r++) {
        int dt = EDST[r];
        ab.r[r].csr_src = csr_src + (size_t)r * NE_EDGES;
        ab.r[r].off  = offsets + (size_t)r * (NT_NODES + 1);
        ab.r[r].q    = qbf + (size_t)dt * NF;
        ab.r[r].kv   = (ESRC[r] == 0) ? kv0 : kv1;
        ab.r[r].Arel = a_rel + (size_t)(l * NRL + r) * NH * HD * HD;
        ab.r[r].Mrel = m_rel + (size_t)(l * NRL + r) * NH * HD * HD;
        ab.r[r].prel = p_rel + (size_t)(l * NRL + r) * NH;
        ab.r[r].agg  = (r == 2) ? aggX : (agg + (size_t)dt * NF);
      }
      attn_fused<<<dim3((NT_NODES + 3) / 4, NRL), 256, 0, stream>>>(ab);
    }

    // out: hs_new[t] = a_s*(gelu(agg[t] [+aggX]) @ a_w + a_b) + (1-a_s)*hs[t]
    {
      GemmBatch gb{};
      for (int t = 0; t < 3; t++) {
        gb.t[t].A = agg + (size_t)t * NF;
        gb.t[t].A2 = (t == 0) ? aggX : nullptr;
        gb.t[t].W = a_w + (size_t)(l * NTY + t) * FDIM * FDIM;
        gb.t[t].bias = a_b + (size_t)(l * NTY + t) * FDIM;
        gb.t[t].C = alt + (size_t)t * NF;
        gb.t[t].oldh = cur + (size_t)t * NF;
        gb.t[t].skipp = skip + (size_t)(l * NTY + t);
      }
      gemm_f32<1, 1, 0><<<dim3(gemm_gx, 1, 3), 256, 0, stream>>>(gb, NT_NODES);
    }
    float* tmp = cur; cur = alt; alt = tmp;
  }

  const int NN = 3 * NT_NODES;
  scatter_out<<<dim3((NN * 32 + 255) / 256), 256, 0, stream>>>(
      cur, cur + NF, cur + 2 * NF, ntype, out, NN);
}

// Round 10
// 686.416 us; speedup vs baseline: 1.6666x; 1.0040x over previous
//
#include <hip/hip_runtime.h>
#include <math.h>

#define NT_NODES 30000
#define NE_EDGES 200000
#define NTY 3
#define NRL 4
#define NLY 2
#define NH 8
#define HD 16
#define FDIM 128
#define SCAN_BLOCKS 118   // ceil(30000/256)

typedef unsigned short u16;
typedef unsigned int u32;
typedef __attribute__((ext_vector_type(8))) short bf16x8;
typedef __attribute__((ext_vector_type(4))) float f32x4;

__device__ __forceinline__ float bf2f(u16 u) {
  return __uint_as_float(((u32)u) << 16);
}
__device__ __forceinline__ u16 f2bf(float f) {   // RNE
  u32 u = __float_as_uint(f);
  return (u16)((u + 0x7FFFu + ((u >> 16) & 1u)) >> 16);
}

__device__ __forceinline__ float gelu_f(float x) {
  return 0.5f * x * (1.f + erff(x * 0.7071067811865475f));
}

// -------------------------------------------------- weight prep (bf16 W^T) --
// 23 matrices: [0..13] QKV (7/layer), [14..16] lin_w, [17..22] a_w
struct WtBatch { const float* w[23]; };
__global__ __launch_bounds__(256) void wt_prep(WtBatch wb, u16* wt) {
  const float* w = wb.w[blockIdx.x];
  u16* o = wt + (size_t)blockIdx.x * FDIM * FDIM;
  for (int i = threadIdx.x; i < FDIM * FDIM; i += 256) {
    int n = i >> 7, k = i & 127;            // o[n][k] = w[k][n]
    o[i] = f2bf(w[(size_t)k * FDIM + n]);
  }
}

// ------------------------------------------------------- MFMA core pieces ---
// Block: 256 thr (4 waves), tile 64 rows; wave w -> cols 32w..32w+31.
// LDS XOR-swizzle on 16B granules: granule k8 stored at k8 ^ (row&7).
// C/D layout: col=lane&15, row=(lane>>4)*4+rr (verified R9).

// --- bf16-output variant (Q/K/V). mode: 0=plain [N][ldc], 1=K-pack, 2=V-pack
// packed row = 256 u16; K col c -> 4*(c>>1)+(c&1); V adds +2.
struct GemmTaskB { const float* A; const u16* WT; const float* bias; u16* C; int ldc; int mode; };
struct GemmBatchB { GemmTaskB t[7]; };

__global__ __launch_bounds__(256) void gemm_mfma_b(GemmBatchB gb, int M) {
  const GemmTaskB tk = gb.t[blockIdx.z];
  const int tid = threadIdx.x;
  const int wv = tid >> 6;
  const int lane = tid & 63;
  const int row0 = blockIdx.x * 64;

  __shared__ u16 As[64 * 128];
  __shared__ u16 Bt[128 * 128];

  #pragma unroll
  for (int i = 0; i < 4; i++) {
    int g = tid + 256 * i;
    int r = g >> 4, k8 = g & 15;
    int grow = row0 + r;
    float4 va = make_float4(0.f, 0.f, 0.f, 0.f), vb = va;
    if (grow < M) {
      const float* ap = tk.A + (size_t)grow * FDIM + k8 * 8;
      va = *(const float4*)ap;
      vb = *(const float4*)(ap + 4);
    }
    u32 w0 = (u32)f2bf(va.x) | ((u32)f2bf(va.y) << 16);
    u32 w1 = (u32)f2bf(va.z) | ((u32)f2bf(va.w) << 16);
    u32 w2 = (u32)f2bf(vb.x) | ((u32)f2bf(vb.y) << 16);
    u32 w3 = (u32)f2bf(vb.z) | ((u32)f2bf(vb.w) << 16);
    u32* dst = (u32*)(As + r * 128 + ((k8 ^ (r & 7)) * 8));
    dst[0] = w0; dst[1] = w1; dst[2] = w2; dst[3] = w3;
  }
  #pragma unroll
  for (int i = 0; i < 8; i++) {
    int g = tid + 256 * i;
    int n = g >> 4, k8 = g & 15;
    uint4 v = *(const uint4*)(tk.WT + (size_t)n * FDIM + k8 * 8);
    *(uint4*)(Bt + n * 128 + ((k8 ^ (n & 7)) * 8)) = v;
  }
  __syncthreads();

  f32x4 acc[4][2] = {};
  const int rsel = lane & 15, ksel = lane >> 4;
  #pragma unroll
  for (int ks = 0; ks < 4; ks++) {
    int kg = ks * 4 + ksel;
    bf16x8 af[4], bfr[2];
    #pragma unroll
    for (int i = 0; i < 4; i++) {
      int r = 16 * i + rsel;
      af[i] = *(const bf16x8*)(As + r * 128 + ((kg ^ (r & 7)) * 8));
    }
    #pragma unroll
    for (int j = 0; j < 2; j++) {
      int n = 32 * wv + 16 * j + rsel;
      bfr[j] = *(const bf16x8*)(Bt + n * 128 + ((kg ^ (n & 7)) * 8));
    }
    #pragma unroll
    for (int i = 0; i < 4; i++)
      #pragma unroll
      for (int j = 0; j < 2; j++)
        acc[i][j] = __builtin_amdgcn_mfma_f32_16x16x32_bf16(af[i], bfr[j], acc[i][j], 0, 0, 0);
  }

  const int ldc = tk.ldc, mode = tk.mode;
  float bj[2];
  int cm[2];
  #pragma unroll
  for (int j = 0; j < 2; j++) {
    int col = 32 * wv + 16 * j + rsel;
    bj[j] = tk.bias[col];
    cm[j] = (mode == 0) ? col : ((((col >> 1) << 2) | (col & 1)) + ((mode == 2) ? 2 : 0));
  }
  #pragma unroll
  for (int i = 0; i < 4; i++) {
    #pragma unroll
    for (int rr = 0; rr < 4; rr++) {
      int grow = row0 + 16 * i + (lane >> 4) * 4 + rr;
      if (grow >= M) continue;
      #pragma unroll
      for (int j = 0; j < 2; j++)
        tk.C[(size_t)grow * ldc + cm[j]] = f2bf(acc[i][j][rr] + bj[j]);
    }
  }
}

// --- f32-output variant (in-proj RELU / out-GEMM gelu+skip)
struct GemmTaskF {
  const float* A; const float* A2; const u16* WT; const float* bias;
  float* C; const float* oldh; const float* skipp;
};
struct GemmBatchF { GemmTaskF t[3]; };

template<int GELU_A, int EPI_SKIP, int RELU>
__global__ __launch_bounds__(256) void gemm_mfma_f(GemmBatchF gb, int M) {
  const GemmTaskF tk = gb.t[blockIdx.z];
  const int tid = threadIdx.x;
  const int wv = tid >> 6;
  const int lane = tid & 63;
  const int row0 = blockIdx.x * 64;

  __shared__ u16 As[64 * 128];
  __shared__ u16 Bt[128 * 128];

  #pragma unroll
  for (int i = 0; i < 4; i++) {
    int g = tid + 256 * i;
    int r = g >> 4, k8 = g & 15;
    int grow = row0 + r;
    float4 va = make_float4(0.f, 0.f, 0.f, 0.f), vb = va;
    if (grow < M) {
      const float* ap = tk.A + (size_t)grow * FDIM + k8 * 8;
      va = *(const float4*)ap;
      vb = *(const float4*)(ap + 4);
      if (GELU_A && tk.A2) {
        const float* ap2 = tk.A2 + (size_t)grow * FDIM + k8 * 8;
        float4 w = *(const float4*)ap2;
        float4 z = *(const float4*)(ap2 + 4);
        va.x += w.x; va.y += w.y; va.z += w.z; va.w += w.w;
        vb.x += z.x; vb.y += z.y; vb.z += z.z; vb.w += z.w;
      }
      if (GELU_A) {
        va.x = gelu_f(va.x); va.y = gelu_f(va.y); va.z = gelu_f(va.z); va.w = gelu_f(va.w);
        vb.x = gelu_f(vb.x); vb.y = gelu_f(vb.y); vb.z = gelu_f(vb.z); vb.w = gelu_f(vb.w);
      }
    }
    u32 w0 = (u32)f2bf(va.x) | ((u32)f2bf(va.y) << 16);
    u32 w1 = (u32)f2bf(va.z) | ((u32)f2bf(va.w) << 16);
    u32 w2 = (u32)f2bf(vb.x) | ((u32)f2bf(vb.y) << 16);
    u32 w3 = (u32)f2bf(vb.z) | ((u32)f2bf(vb.w) << 16);
    u32* dst = (u32*)(As + r * 128 + ((k8 ^ (r & 7)) * 8));
    dst[0] = w0; dst[1] = w1; dst[2] = w2; dst[3] = w3;
  }
  #pragma unroll
  for (int i = 0; i < 8; i++) {
    int g = tid + 256 * i;
    int n = g >> 4, k8 = g & 15;
    uint4 v = *(const uint4*)(tk.WT + (size_t)n * FDIM + k8 * 8);
    *(uint4*)(Bt + n * 128 + ((k8 ^ (n & 7)) * 8)) = v;
  }
  __syncthreads();

  f32x4 acc[4][2] = {};
  const int rsel = lane & 15, ksel = lane >> 4;
  #pragma unroll
  for (int ks = 0; ks < 4; ks++) {
    int kg = ks * 4 + ksel;
    bf16x8 af[4], bfr[2];
    #pragma unroll
    for (int i = 0; i < 4; i++) {
      int r = 16 * i + rsel;
      af[i] = *(const bf16x8*)(As + r * 128 + ((kg ^ (r & 7)) * 8));
    }
    #pragma unroll
    for (int j = 0; j < 2; j++) {
      int n = 32 * wv + 16 * j + rsel;
      bfr[j] = *(const bf16x8*)(Bt + n * 128 + ((kg ^ (n & 7)) * 8));
    }
    #pragma unroll
    for (int i = 0; i < 4; i++)
      #pragma unroll
      for (int j = 0; j < 2; j++)
        acc[i][j] = __builtin_amdgcn_mfma_f32_16x16x32_bf16(af[i], bfr[j], acc[i][j], 0, 0, 0);
  }

  float a_s = 0.f, b_s = 0.f;
  if (EPI_SKIP) { a_s = 1.f / (1.f + expf(-tk.skipp[0])); b_s = 1.f - a_s; }
  float bj[2];
  int colj[2];
  #pragma unroll
  for (int j = 0; j < 2; j++) {
    colj[j] = 32 * wv + 16 * j + rsel;
    bj[j] = tk.bias[colj[j]];
  }
  #pragma unroll
  for (int i = 0; i < 4; i++) {
    #pragma unroll
    for (int rr = 0; rr < 4; rr++) {
      int grow = row0 + 16 * i + (lane >> 4) * 4 + rr;
      if (grow >= M) continue;
      #pragma unroll
      for (int j = 0; j < 2; j++) {
        float v = acc[i][j][rr] + bj[j];
        if (RELU) v = fmaxf(v, 0.f);
        if (EPI_SKIP) v = a_s * v + b_s * tk.oldh[(size_t)grow * FDIM + colj[j]];
        tk.C[(size_t)grow * FDIM + colj[j]] = v;
      }
    }
  }
}

// ------------------------------------------------------------- CSR build ----
__global__ __launch_bounds__(256) void csr_hist(const int* __restrict__ edge_index,
                                                int* __restrict__ counts) {
  int idx = blockIdx.x * 256 + threadIdx.x;
  if (idx >= NRL * NE_EDGES) return;
  int r = idx / NE_EDGES, e = idx - r * NE_EDGES;
  int d = edge_index[(size_t)(r * 2 + 1) * NE_EDGES + e];
  atomicAdd(&counts[r * NT_NODES + d], 1);
}

__global__ __launch_bounds__(256) void scan_block(const int* __restrict__ counts,
                                                  int* __restrict__ off,
                                                  int* __restrict__ aux) {
  int r = blockIdx.y, b = blockIdx.x, t = threadIdx.x;
  int i = b * 256 + t;
  int v = (i < NT_NODES) ? counts[r * NT_NODES + i] : 0;
  __shared__ int lds[256];
  lds[t] = v;
  __syncthreads();
  #pragma unroll
  for (int dlt = 1; dlt < 256; dlt <<= 1) {
    int x = (t >= dlt) ? lds[t - dlt] : 0;
    __syncthreads();
    lds[t] += x;
    __syncthreads();
  }
  if (i < NT_NODES) off[(size_t)r * (NT_NODES + 1) + i] = lds[t] - v;
  if (t == 255) aux[r * SCAN_BLOCKS + b] = lds[255];
}

__global__ __launch_bounds__(128) void scan_aux(const int* __restrict__ aux,
                                                int* __restrict__ auxe,
                                                int* __restrict__ off) {
  int r = blockIdx.x, t = threadIdx.x;
  __shared__ int lds[128];
  int v = (t < SCAN_BLOCKS) ? aux[r * SCAN_BLOCKS + t] : 0;
  lds[t] = v;
  __syncthreads();
  #pragma unroll
  for (int dlt = 1; dlt < 128; dlt <<= 1) {
    int x = (t >= dlt) ? lds[t - dlt] : 0;
    __syncthreads();
    lds[t] += x;
    __syncthreads();
  }
  if (t < SCAN_BLOCKS) auxe[r * SCAN_BLOCKS + t] = lds[t] - v;
  if (t == 127) off[(size_t)r * (NT_NODES + 1) + NT_NODES] = lds[127];
}

__global__ __launch_bounds__(256) void scan_add(const int* __restrict__ auxe,
                                                int* __restrict__ off,
                                                int* __restrict__ cursor) {
  int r = blockIdx.y, b = blockIdx.x, t = threadIdx.x;
  int i = b * 256 + t;
  if (i >= NT_NODES) return;
  int val = off[(size_t)r * (NT_NODES + 1) + i] + auxe[r * SCAN_BLOCKS + b];
  off[(size_t)r * (NT_NODES + 1) + i] = val;
  cursor[r * NT_NODES + i] = val;
}

__global__ __launch_bounds__(256) void csr_scatter(const int* __restrict__ edge_index,
                                                   int* __restrict__ cursor,
                                                   int* __restrict__ csr_src) {
  int idx = blockIdx.x * 256 + threadIdx.x;
  if (idx >= NRL * NE_EDGES) return;
  int r = idx / NE_EDGES, e = idx - r * NE_EDGES;
  int s = edge_index[(size_t)(r * 2 + 0) * NE_EDGES + e];
  int d = edge_index[(size_t)(r * 2 + 1) * NE_EDGES + e];
  int pos = atomicAdd(&cursor[r * NT_NODES + d], 1);
  csr_src[(size_t)r * NE_EDGES + pos] = s;
}

__global__ void csr_pad(int* __restrict__ pad) {
  if (threadIdx.x < 8) pad[threadIdx.x] = 0;
}

// ---------------------------------------------------- fused attention -------
// One wave per dst node. PACKED KV table [N][256] u16: lane l reads ushort4
// = (K[2l], K[2l+1], V[2l], V[2l+1]) -> ONE 8B gather per edge (half the
// request count of split K/V at the same bytes). 8-edge batches; transposed
// pair-reduce butterfly for the 8 dots (7 shfl, 1 exp).
struct AttnRel {
  const int* csr_src; const int* off;
  const u16* q;        // bf16 Q of dst type [N,128]
  const u16* kv;       // packed bf16 KV of src type [N,256]
  const float* Arel;   // [8][16][16]
  const float* Mrel;   // [8][16][16]
  const float* prel;   // [8]
  float* agg;          // output [N,128] (overwritten)
};
struct AttnBatch { AttnRel r[4]; };

__global__ __launch_bounds__(256) void attn_fused(AttnBatch ab) {
  const AttnRel rp = ab.r[blockIdx.y];
  const int wave = threadIdx.x >> 6;
  const int lane = threadIdx.x & 63;
  const int d = blockIdx.x * 4 + wave;
  if (d >= NT_NODES) return;
  const int h = lane >> 3;         // head 0..7
  const int el = lane & 7;         // pair index (channels 2el,2el+1)
  const int grp = h << 3;

  // ---- q' = (A_h @ q_h) * p_h/4 via shfl within 8-lane head groups ----
  ushort2 qu = ((const ushort2*)rp.q)[(size_t)d * 64 + lane];
  float q0 = bf2f(qu.x), q1 = bf2f(qu.y);
  const float* A = rp.Arel + (size_t)h * 256;
  float qp0 = 0.f, qp1 = 0.f;
  #pragma unroll
  for (int ee = 0; ee < 8; ee++) {
    float qa = __shfl(q0, grp + ee, 64);
    float qb = __shfl(q1, grp + ee, 64);
    qp0 += A[(2 * el) * 16 + 2 * ee] * qa + A[(2 * el) * 16 + 2 * ee + 1] * qb;
    qp1 += A[(2 * el + 1) * 16 + 2 * ee] * qa + A[(2 * el + 1) * 16 + 2 * ee + 1] * qb;
  }
  float sc = rp.prel[h] * 0.25f;
  qp0 *= sc; qp1 *= sc;

  const ushort4* KVp = (const ushort4*)rp.kv;   // [N][64] ushort4
  const int* __restrict__ cs = rp.csr_src;
  int lo = rp.off[d], hi = rp.off[d + 1];
  lo = __builtin_amdgcn_readfirstlane(lo);
  hi = __builtin_amdgcn_readfirstlane(hi);
  float acc0 = 0.f, acc1 = 0.f, ssum = 0.f;
  for (int pos = lo; pos < hi; pos += 8) {
    int s0 = cs[pos + 0], s1 = cs[pos + 1], s2 = cs[pos + 2], s3 = cs[pos + 3];
    int s4 = cs[pos + 4], s5 = cs[pos + 5], s6 = cs[pos + 6], s7 = cs[pos + 7];
    ushort4 a0 = KVp[(size_t)s0 * 64 + lane], a1 = KVp[(size_t)s1 * 64 + lane];
    ushort4 a2 = KVp[(size_t)s2 * 64 + lane], a3 = KVp[(size_t)s3 * 64 + lane];
    ushort4 a4 = KVp[(size_t)s4 * 64 + lane], a5 = KVp[(size_t)s5 * 64 + lane];
    ushort4 a6 = KVp[(size_t)s6 * 64 + lane], a7 = KVp[(size_t)s7 * 64 + lane];
    float p0 = qp0 * bf2f(a0.x) + qp1 * bf2f(a0.y);
    float p1 = qp0 * bf2f(a1.x) + qp1 * bf2f(a1.y);
    float p2 = qp0 * bf2f(a2.x) + qp1 * bf2f(a2.y);
    float p3 = qp0 * bf2f(a3.x) + qp1 * bf2f(a3.y);
    float p4 = qp0 * bf2f(a4.x) + qp1 * bf2f(a4.y);
    float p5 = qp0 * bf2f(a5.x) + qp1 * bf2f(a5.y);
    float p6 = qp0 * bf2f(a6.x) + qp1 * bf2f(a6.y);
    float p7 = qp0 * bf2f(a7.x) + qp1 * bf2f(a7.y);
    // transposed pair-reduce butterfly: lane el ends with edge el's logit
    float s01 = (el & 1) ? p0 : p1, c01 = (el & 1) ? p1 : p0;
    float s23 = (el & 1) ? p2 : p3, c23 = (el & 1) ? p3 : p2;
    float s45 = (el & 1) ? p4 : p5, c45 = (el & 1) ? p5 : p4;
    float s67 = (el & 1) ? p6 : p7, c67 = (el & 1) ? p7 : p6;
    float r01 = c01 + __shfl_xor(s01, 1, 64);
    float r23 = c23 + __shfl_xor(s23, 1, 64);
    float r45 = c45 + __shfl_xor(s45, 1, 64);
    float r67 = c67 + __shfl_xor(s67, 1, 64);
    float sA = (el & 2) ? r01 : r23, cA = (el & 2) ? r23 : r01;
    float sB = (el & 2) ? r45 : r67, cB = (el & 2) ? r67 : r45;
    float rA = cA + __shfl_xor(sA, 2, 64);
    float rB = cB + __shfl_xor(sB, 2, 64);
    float sC = (el & 4) ? rA : rB, cC = (el & 4) ? rB : rA;
    float rF = cC + __shfl_xor(sC, 4, 64);
    int rem = hi - pos;   // scalar
    float e = (el < rem) ? __expf(rF) : 0.f;
    float e0 = __shfl(e, grp + 0, 64), e1 = __shfl(e, grp + 1, 64);
    float e2 = __shfl(e, grp + 2, 64), e3 = __shfl(e, grp + 3, 64);
    float e4 = __shfl(e, grp + 4, 64), e5 = __shfl(e, grp + 5, 64);
    float e6 = __shfl(e, grp + 6, 64), e7 = __shfl(e, grp + 7, 64);
    acc0 += e0 * bf2f(a0.z) + e1 * bf2f(a1.z) + e2 * bf2f(a2.z) + e3 * bf2f(a3.z)
          + e4 * bf2f(a4.z) + e5 * bf2f(a5.z) + e6 * bf2f(a6.z) + e7 * bf2f(a7.z);
    acc1 += e0 * bf2f(a0.w) + e1 * bf2f(a1.w) + e2 * bf2f(a2.w) + e3 * bf2f(a3.w)
          + e4 * bf2f(a4.w) + e5 * bf2f(a5.w) + e6 * bf2f(a6.w) + e7 * bf2f(a7.w);
    ssum += ((e0 + e1) + (e2 + e3)) + ((e4 + e5) + (e6 + e7));
  }
  float inv = 1.f / (ssum + 1e-16f);
  float S0 = acc0 * inv, S1 = acc1 * inv;

  // ---- apply M_rel: out_j = sum_d2 S[d2] * M[h][d2][j] ----
  const float* M = rp.Mrel + (size_t)h * 256;
  float o0 = 0.f, o1 = 0.f;
  #pragma unroll
  for (int dd = 0; dd < 8; dd++) {
    float sa = __shfl(S0, grp + dd, 64);
    float sb = __shfl(S1, grp + dd, 64);
    o0 += sa * M[(2 * dd) * 16 + 2 * el] + sb * M[(2 * dd + 1) * 16 + 2 * el];
    o1 += sa * M[(2 * dd) * 16 + 2 * el + 1] + sb * M[(2 * dd + 1) * 16 + 2 * el + 1];
  }
  float* ap = rp.agg + (size_t)d * FDIM + 2 * lane;
  *(float2*)ap = make_float2(o0, o1);
}

// ---------------------------------------------------------------- scatter ---
__global__ __launch_bounds__(256) void scatter_out(const float* h0, const float* h1,
                                                   const float* h2, const int* ntype,
                                                   float* out, int NN) {
  int idx = blockIdx.x * 256 + threadIdx.x;
  if (idx >= NN * 32) return;
  int i = idx >> 5, c4 = idx & 31;
  int t = ntype[i];
  const float* hp = (t == 0) ? h0 : ((t == 1) ? h1 : h2);
  int local = i - t * NT_NODES;
  ((float4*)out)[idx] = ((const float4*)hp)[(size_t)local * 32 + c4];
}

// ------------------------------------------------------------------- host ---
static const int ESRC[NRL] = {0, 0, 1, 0};
static const int EDST[NRL] = {0, 1, 0, 2};

extern "C" void kernel_launch(void* const* d_in, const int* in_sizes, int n_in,
                              void* d_out, int out_size, void* d_ws, size_t ws_size,
                              hipStream_t stream) {
  const float* x[3] = {(const float*)d_in[0], (const float*)d_in[1], (const float*)d_in[2]};
  const float* lin_w = (const float*)d_in[4];
  const float* lin_b = (const float*)d_in[5];
  const float* k_w   = (const float*)d_in[6];
  const float* k_b   = (const float*)d_in[7];
  const float* q_w   = (const float*)d_in[8];
  const float* q_b   = (const float*)d_in[9];
  const float* v_w   = (const float*)d_in[10];
  const float* v_b   = (const float*)d_in[11];
  const float* a_w   = (const float*)d_in[12];
  const float* a_b   = (const float*)d_in[13];
  const float* skip  = (const float*)d_in[14];
  const float* a_rel = (const float*)d_in[15];
  const float* m_rel = (const float*)d_in[16];
  const float* p_rel = (const float*)d_in[17];
  const int* edge_index = (const int*)d_in[18];
  const int* ntype   = (const int*)d_in[19];
  float* out = (float*)d_out;

  const size_t NF = (size_t)NT_NODES * FDIM;
  float* p = (float*)d_ws;
  auto alloc = [&](size_t n) { float* r = p; p += n; return r; };
  float* bufA = alloc(3 * NF);                    // h (ping)
  float* bufB = alloc(3 * NF);                    // h (pong); bf16 Q aliases
  float* agg  = alloc(3 * NF);                    // rels 0,1,3
  float* aggX = alloc(NF);                        // rel 2 (summed in out-GEMM)
  u16* kv0 = (u16*)alloc(NF);                     // packed K|V, src type 0 [N][256]
  u16* kv1 = (u16*)alloc(NF);                     // packed K|V, src type 1
  u16* wt  = (u16*)alloc(23 * FDIM * FDIM / 2);   // 23 bf16 W^T matrices
  int* counts  = (int*)(p);
  int* cursor  = counts + NRL * NT_NODES;
  int* offsets = cursor + NRL * NT_NODES;
  int* aux     = offsets + NRL * (NT_NODES + 1);
  int* auxe    = aux + NRL * SCAN_BLOCKS;
  int* csr_src = auxe + NRL * SCAN_BLOCKS;        // [4][E] + 8 slack

  const int gemm_gx = (NT_NODES + 63) / 64;   // 469

  // ---- weight prep: bf16 W^T (QKV 14, lin 3, a_w 6) ----
  {
    WtBatch wb{};
    for (int l = 0; l < NLY; l++) {
      for (int t = 0; t < 3; t++)
        wb.w[l * 7 + t] = q_w + (size_t)(l * NTY + t) * FDIM * FDIM;
      wb.w[l * 7 + 3] = k_w + (size_t)(l * NTY + 0) * FDIM * FDIM;
      wb.w[l * 7 + 4] = v_w + (size_t)(l * NTY + 0) * FDIM * FDIM;
      wb.w[l * 7 + 5] = k_w + (size_t)(l * NTY + 1) * FDIM * FDIM;
      wb.w[l * 7 + 6] = v_w + (size_t)(l * NTY + 1) * FDIM * FDIM;
    }
    for (int t = 0; t < 3; t++)
      wb.w[14 + t] = lin_w + (size_t)t * FDIM * FDIM;
    for (int l = 0; l < NLY; l++)
      for (int t = 0; t < 3; t++)
        wb.w[17 + l * 3 + t] = a_w + (size_t)(l * NTY + t) * FDIM * FDIM;
    wt_prep<<<dim3(23), 256, 0, stream>>>(wb, wt);
  }

  // ---- CSR build ----
  hipMemsetAsync(counts, 0, NRL * NT_NODES * sizeof(int), stream);
  csr_hist<<<dim3((NRL * NE_EDGES + 255) / 256), 256, 0, stream>>>(edge_index, counts);
  scan_block<<<dim3(SCAN_BLOCKS, NRL), 256, 0, stream>>>(counts, offsets, aux);
  scan_aux<<<dim3(NRL), 128, 0, stream>>>(aux, auxe, offsets);
  scan_add<<<dim3(SCAN_BLOCKS, NRL), 256, 0, stream>>>(auxe, offsets, cursor);
  csr_scatter<<<dim3((NRL * NE_EDGES + 255) / 256), 256, 0, stream>>>(edge_index, cursor, csr_src);
  csr_pad<<<dim3(1), 64, 0, stream>>>(csr_src + (size_t)NRL * NE_EDGES);

  // input projection: hs[t] = relu(x_t @ lin_w[t] + lin_b[t])  (MFMA, f32 out)
  {
    GemmBatchF gb{};
    for (int t = 0; t < 3; t++) {
      gb.t[t].A = x[t];
      gb.t[t].A2 = nullptr;
      gb.t[t].WT = wt + (size_t)(14 + t) * FDIM * FDIM;
      gb.t[t].bias = lin_b + (size_t)t * FDIM;
      gb.t[t].C = bufA + (size_t)t * NF;
      gb.t[t].oldh = nullptr; gb.t[t].skipp = nullptr;
    }
    gemm_mfma_f<0, 0, 1><<<dim3(gemm_gx, 1, 3), 256, 0, stream>>>(gb, NT_NODES);
  }

  float* cur = bufA;
  float* alt = bufB;
  for (int l = 0; l < NLY; l++) {
    u16* qbf = (u16*)alt;

    // Q (3 types) + packed K/V (src types 0,1) — MFMA bf16, one launch
    {
      GemmBatchB gb{};
      for (int t = 0; t < 3; t++) {
        gb.t[t].A = cur + (size_t)t * NF;
        gb.t[t].WT = wt + (size_t)(l * 7 + t) * FDIM * FDIM;
        gb.t[t].bias = q_b + (size_t)(l * NTY + t) * FDIM;
        gb.t[t].C = qbf + (size_t)t * NF;
        gb.t[t].ldc = FDIM; gb.t[t].mode = 0;
      }
      gb.t[3].A = cur;  gb.t[3].WT = wt + (size_t)(l * 7 + 3) * FDIM * FDIM;
      gb.t[3].bias = k_b + (size_t)(l * NTY + 0) * FDIM;
      gb.t[3].C = kv0;  gb.t[3].ldc = 256;  gb.t[3].mode = 1;
      gb.t[4].A = cur;  gb.t[4].WT = wt + (size_t)(l * 7 + 4) * FDIM * FDIM;
      gb.t[4].bias = v_b + (size_t)(l * NTY + 0) * FDIM;
      gb.t[4].C = kv0;  gb.t[4].ldc = 256;  gb.t[4].mode = 2;
      gb.t[5].A = cur + NF;  gb.t[5].WT = wt + (size_t)(l * 7 + 5) * FDIM * FDIM;
      gb.t[5].bias = k_b + (size_t)(l * NTY + 1) * FDIM;
      gb.t[5].C = kv1;  gb.t[5].ldc = 256;  gb.t[5].mode = 1;
      gb.t[6].A = cur + NF;  gb.t[6].WT = wt + (size_t)(l * 7 + 6) * FDIM * FDIM;
      gb.t[6].bias = v_b + (size_t)(l * NTY + 1) * FDIM;
      gb.t[6].C = kv1;  gb.t[6].ldc = 256;  gb.t[6].mode = 2;
      gemm_mfma_b<<<dim3(gemm_gx, 1, 7), 256, 0, stream>>>(gb, NT_NODES);
    }

    // attention: all 4 relations, one launch
    {
      AttnBatch ab{};
      for (int r = 0; r < NRL; r++) {
        int dt = EDST[r];
        ab.r[r].csr_src = csr_src + (size_t)r * NE_EDGES;
        ab.r[r].off  = offsets + (size_t)r * (NT_NODES + 1);
        ab.r[r].q    = qbf + (size_t)dt * NF;
        ab.r[r].kv   = (ESRC[r] == 0) ? kv0 : kv1;
        ab.r[r].Arel = a_rel + (size_t)(l * NRL + r) * NH * HD * HD;
        ab.r[r].Mrel = m_rel + (size_t)(l * NRL + r) * NH * HD * HD;
        ab.r[r].prel = p_rel + (size_t)(l * NRL + r) * NH;
        ab.r[r].agg  = (r == 2) ? aggX : (agg + (size_t)dt * NF);
      }
      attn_fused<<<dim3((NT_NODES + 3) / 4, NRL), 256, 0, stream>>>(ab);
    }

    // out: hs_new[t] = a_s*(gelu(agg[t] [+aggX]) @ a_w + a_b) + (1-a_s)*hs[t]
    {
      GemmBatchF gb{};
      for (int t = 0; t < 3; t++) {
        gb.t[t].A = agg + (size_t)t * NF;
        gb.t[t].A2 = (t == 0) ? aggX : nullptr;
        gb.t[t].WT = wt + (size_t)(17 + l * 3 + t) * FDIM * FDIM;
        gb.t[t].bias = a_b + (size_t)(l * NTY + t) * FDIM;
        gb.t[t].C = alt + (size_t)t * NF;
        gb.t[t].oldh = cur + (size_t)t * NF;
        gb.t[t].skipp = skip + (size_t)(l * NTY + t);
      }
      gemm_mfma_f<1, 1, 0><<<dim3(gemm_gx, 1, 3), 256, 0, stream>>>(gb, NT_NODES);
    }
    float* tmp = cur; cur = alt; alt = tmp;
  }

  const int NN = 3 * NT_NODES;
  scatter_out<<<dim3((NN * 32 + 255) / 256), 256, 0, stream>>>(
      cur, cur + NF, cur + 2 * NF, ntype, out, NN);
}

// Round 11
// 663.291 us; speedup vs baseline: 1.7248x; 1.0349x over previous
//
#include <hip/hip_runtime.h>
#include <math.h>

#define NT_NODES 30000
#define NE_EDGES 200000
#define NTY 3
#define NRL 4
#define NLY 2
#define NH 8
#define HD 16
#define FDIM 128
#define SCAN_BLOCKS 118   // ceil(30000/256)

typedef unsigned short u16;
typedef unsigned int u32;
typedef __attribute__((ext_vector_type(8))) short bf16x8;
typedef __attribute__((ext_vector_type(4))) float f32x4;

__device__ __forceinline__ float bf2f(u16 u) {
  return __uint_as_float(((u32)u) << 16);
}
__device__ __forceinline__ u16 f2bf(float f) {   // RNE
  u32 u = __float_as_uint(f);
  return (u16)((u + 0x7FFFu + ((u >> 16) & 1u)) >> 16);
}

__device__ __forceinline__ float gelu_f(float x) {
  return 0.5f * x * (1.f + erff(x * 0.7071067811865475f));
}

// -------------------------------------------------- weight prep (bf16 W^T) --
// 23 matrices: [0..13] QKV (7/layer), [14..16] lin_w, [17..22] a_w
struct WtBatch { const float* w[23]; };
__global__ __launch_bounds__(256) void wt_prep(WtBatch wb, u16* wt) {
  const float* w = wb.w[blockIdx.x];
  u16* o = wt + (size_t)blockIdx.x * FDIM * FDIM;
  for (int i = threadIdx.x; i < FDIM * FDIM; i += 256) {
    int n = i >> 7, k = i & 127;            // o[n][k] = w[k][n]
    o[i] = f2bf(w[(size_t)k * FDIM + n]);
  }
}

// ------------------------------------------------------- MFMA core ----------
// Block: 256 thr (4 waves), tile 64 rows; wave w -> cols 32w..32w+31.
// LDS XOR-swizzle on 16B granules: granule k8 stored at k8 ^ (row&7).
// C/D layout: col=lane&15, row=(lane>>4)*4+rr (verified R9).

// --- fused QKV: A (bf16 h) staged once, MFMA A-fragments held in registers,
// loop over up to 3 weight matrices -> bf16 outputs.
struct QkvOut { const u16* WT; const float* bias; u16* C; int ldc; };
struct QkvTask { const u16* A; int nout; QkvOut o[3]; };
struct QkvBatch { QkvTask t[3]; };

__global__ __launch_bounds__(256) void gemm_qkv(QkvBatch gb, int M) {
  const QkvTask tk = gb.t[blockIdx.z];
  const int tid = threadIdx.x;
  const int wv = tid >> 6;
  const int lane = tid & 63;
  const int row0 = blockIdx.x * 64;

  __shared__ u16 As[64 * 128];
  __shared__ u16 Bt[128 * 128];

  // stage A (bf16 direct copy, swizzled granules)
  #pragma unroll
  for (int i = 0; i < 4; i++) {
    int g = tid + 256 * i;
    int r = g >> 4, k8 = g & 15;
    int grow = row0 + r;
    uint4 v = make_uint4(0, 0, 0, 0);
    if (grow < M) v = *(const uint4*)(tk.A + (size_t)grow * FDIM + k8 * 8);
    *(uint4*)(As + r * 128 + ((k8 ^ (r & 7)) * 8)) = v;
  }
  __syncthreads();

  const int rsel = lane & 15, ksel = lane >> 4;
  // A-fragments in registers, reused for all outputs
  bf16x8 af[4][4];
  #pragma unroll
  for (int ks = 0; ks < 4; ks++) {
    int kg = ks * 4 + ksel;
    #pragma unroll
    for (int i = 0; i < 4; i++) {
      int r = 16 * i + rsel;
      af[ks][i] = *(const bf16x8*)(As + r * 128 + ((kg ^ (r & 7)) * 8));
    }
  }

  for (int ot = 0; ot < tk.nout; ot++) {
    const QkvOut oo = tk.o[ot];
    #pragma unroll
    for (int i = 0; i < 8; i++) {
      int g = tid + 256 * i;
      int n = g >> 4, k8 = g & 15;
      uint4 v = *(const uint4*)(oo.WT + (size_t)n * FDIM + k8 * 8);
      *(uint4*)(Bt + n * 128 + ((k8 ^ (n & 7)) * 8)) = v;
    }
    __syncthreads();

    f32x4 acc[4][2] = {};
    #pragma unroll
    for (int ks = 0; ks < 4; ks++) {
      int kg = ks * 4 + ksel;
      bf16x8 bfr[2];
      #pragma unroll
      for (int j = 0; j < 2; j++) {
        int n = 32 * wv + 16 * j + rsel;
        bfr[j] = *(const bf16x8*)(Bt + n * 128 + ((kg ^ (n & 7)) * 8));
      }
      #pragma unroll
      for (int i = 0; i < 4; i++)
        #pragma unroll
        for (int j = 0; j < 2; j++)
          acc[i][j] = __builtin_amdgcn_mfma_f32_16x16x32_bf16(af[ks][i], bfr[j], acc[i][j], 0, 0, 0);
    }

    const int ldc = oo.ldc;
    float bj[2];
    int colj[2];
    #pragma unroll
    for (int j = 0; j < 2; j++) {
      colj[j] = 32 * wv + 16 * j + rsel;
      bj[j] = oo.bias[colj[j]];
    }
    #pragma unroll
    for (int i = 0; i < 4; i++) {
      #pragma unroll
      for (int rr = 0; rr < 4; rr++) {
        int grow = row0 + 16 * i + (lane >> 4) * 4 + rr;
        if (grow >= M) continue;
        #pragma unroll
        for (int j = 0; j < 2; j++)
          oo.C[(size_t)grow * ldc + colj[j]] = f2bf(acc[i][j][rr] + bj[j]);
      }
    }
    __syncthreads();
  }
}

// --- f32-A variant (in-proj RELU / out-GEMM gelu+skip). oldh is bf16.
struct GemmTaskF {
  const float* A; const float* A2; const u16* WT; const float* bias;
  float* C; const u16* oldh; const float* skipp;
};
struct GemmBatchF { GemmTaskF t[3]; };

template<int GELU_A, int EPI_SKIP, int RELU, int BF16_OUT>
__global__ __launch_bounds__(256) void gemm_mfma_f(GemmBatchF gb, int M) {
  const GemmTaskF tk = gb.t[blockIdx.z];
  const int tid = threadIdx.x;
  const int wv = tid >> 6;
  const int lane = tid & 63;
  const int row0 = blockIdx.x * 64;

  __shared__ u16 As[64 * 128];
  __shared__ u16 Bt[128 * 128];

  #pragma unroll
  for (int i = 0; i < 4; i++) {
    int g = tid + 256 * i;
    int r = g >> 4, k8 = g & 15;
    int grow = row0 + r;
    float4 va = make_float4(0.f, 0.f, 0.f, 0.f), vb = va;
    if (grow < M) {
      const float* ap = tk.A + (size_t)grow * FDIM + k8 * 8;
      va = *(const float4*)ap;
      vb = *(const float4*)(ap + 4);
      if (GELU_A && tk.A2) {
        const float* ap2 = tk.A2 + (size_t)grow * FDIM + k8 * 8;
        float4 w = *(const float4*)ap2;
        float4 z = *(const float4*)(ap2 + 4);
        va.x += w.x; va.y += w.y; va.z += w.z; va.w += w.w;
        vb.x += z.x; vb.y += z.y; vb.z += z.z; vb.w += z.w;
      }
      if (GELU_A) {
        va.x = gelu_f(va.x); va.y = gelu_f(va.y); va.z = gelu_f(va.z); va.w = gelu_f(va.w);
        vb.x = gelu_f(vb.x); vb.y = gelu_f(vb.y); vb.z = gelu_f(vb.z); vb.w = gelu_f(vb.w);
      }
    }
    u32 w0 = (u32)f2bf(va.x) | ((u32)f2bf(va.y) << 16);
    u32 w1 = (u32)f2bf(va.z) | ((u32)f2bf(va.w) << 16);
    u32 w2 = (u32)f2bf(vb.x) | ((u32)f2bf(vb.y) << 16);
    u32 w3 = (u32)f2bf(vb.z) | ((u32)f2bf(vb.w) << 16);
    u32* dst = (u32*)(As + r * 128 + ((k8 ^ (r & 7)) * 8));
    dst[0] = w0; dst[1] = w1; dst[2] = w2; dst[3] = w3;
  }
  #pragma unroll
  for (int i = 0; i < 8; i++) {
    int g = tid + 256 * i;
    int n = g >> 4, k8 = g & 15;
    uint4 v = *(const uint4*)(tk.WT + (size_t)n * FDIM + k8 * 8);
    *(uint4*)(Bt + n * 128 + ((k8 ^ (n & 7)) * 8)) = v;
  }
  __syncthreads();

  f32x4 acc[4][2] = {};
  const int rsel = lane & 15, ksel = lane >> 4;
  #pragma unroll
  for (int ks = 0; ks < 4; ks++) {
    int kg = ks * 4 + ksel;
    bf16x8 af[4], bfr[2];
    #pragma unroll
    for (int i = 0; i < 4; i++) {
      int r = 16 * i + rsel;
      af[i] = *(const bf16x8*)(As + r * 128 + ((kg ^ (r & 7)) * 8));
    }
    #pragma unroll
    for (int j = 0; j < 2; j++) {
      int n = 32 * wv + 16 * j + rsel;
      bfr[j] = *(const bf16x8*)(Bt + n * 128 + ((kg ^ (n & 7)) * 8));
    }
    #pragma unroll
    for (int i = 0; i < 4; i++)
      #pragma unroll
      for (int j = 0; j < 2; j++)
        acc[i][j] = __builtin_amdgcn_mfma_f32_16x16x32_bf16(af[i], bfr[j], acc[i][j], 0, 0, 0);
  }

  float a_s = 0.f, b_s = 0.f;
  if (EPI_SKIP) { a_s = 1.f / (1.f + expf(-tk.skipp[0])); b_s = 1.f - a_s; }
  float bj[2];
  int colj[2];
  #pragma unroll
  for (int j = 0; j < 2; j++) {
    colj[j] = 32 * wv + 16 * j + rsel;
    bj[j] = tk.bias[colj[j]];
  }
  #pragma unroll
  for (int i = 0; i < 4; i++) {
    #pragma unroll
    for (int rr = 0; rr < 4; rr++) {
      int grow = row0 + 16 * i + (lane >> 4) * 4 + rr;
      if (grow >= M) continue;
      #pragma unroll
      for (int j = 0; j < 2; j++) {
        float v = acc[i][j][rr] + bj[j];
        if (RELU) v = fmaxf(v, 0.f);
        if (EPI_SKIP) v = a_s * v + b_s * bf2f(tk.oldh[(size_t)grow * FDIM + colj[j]]);
        if (BF16_OUT) ((u16*)tk.C)[(size_t)grow * FDIM + colj[j]] = f2bf(v);
        else tk.C[(size_t)grow * FDIM + colj[j]] = v;
      }
    }
  }
}

// ------------------------------------------------------------- CSR build ----
__global__ __launch_bounds__(256) void csr_hist(const int* __restrict__ edge_index,
                                                int* __restrict__ counts) {
  int idx = blockIdx.x * 256 + threadIdx.x;
  if (idx >= NRL * NE_EDGES) return;
  int r = idx / NE_EDGES, e = idx - r * NE_EDGES;
  int d = edge_index[(size_t)(r * 2 + 1) * NE_EDGES + e];
  atomicAdd(&counts[r * NT_NODES + d], 1);
}

__global__ __launch_bounds__(256) void scan_block(const int* __restrict__ counts,
                                                  int* __restrict__ off,
                                                  int* __restrict__ aux) {
  int r = blockIdx.y, b = blockIdx.x, t = threadIdx.x;
  int i = b * 256 + t;
  int v = (i < NT_NODES) ? counts[r * NT_NODES + i] : 0;
  __shared__ int lds[256];
  lds[t] = v;
  __syncthreads();
  #pragma unroll
  for (int dlt = 1; dlt < 256; dlt <<= 1) {
    int x = (t >= dlt) ? lds[t - dlt] : 0;
    __syncthreads();
    lds[t] += x;
    __syncthreads();
  }
  if (i < NT_NODES) off[(size_t)r * (NT_NODES + 1) + i] = lds[t] - v;
  if (t == 255) aux[r * SCAN_BLOCKS + b] = lds[255];
}

__global__ __launch_bounds__(128) void scan_aux(const int* __restrict__ aux,
                                                int* __restrict__ auxe,
                                                int* __restrict__ off) {
  int r = blockIdx.x, t = threadIdx.x;
  __shared__ int lds[128];
  int v = (t < SCAN_BLOCKS) ? aux[r * SCAN_BLOCKS + t] : 0;
  lds[t] = v;
  __syncthreads();
  #pragma unroll
  for (int dlt = 1; dlt < 128; dlt <<= 1) {
    int x = (t >= dlt) ? lds[t - dlt] : 0;
    __syncthreads();
    lds[t] += x;
    __syncthreads();
  }
  if (t < SCAN_BLOCKS) auxe[r * SCAN_BLOCKS + t] = lds[t] - v;
  if (t == 127) off[(size_t)r * (NT_NODES + 1) + NT_NODES] = lds[127];
}

__global__ __launch_bounds__(256) void scan_add(const int* __restrict__ auxe,
                                                int* __restrict__ off,
                                                int* __restrict__ cursor) {
  int r = blockIdx.y, b = blockIdx.x, t = threadIdx.x;
  int i = b * 256 + t;
  if (i >= NT_NODES) return;
  int val = off[(size_t)r * (NT_NODES + 1) + i] + auxe[r * SCAN_BLOCKS + b];
  off[(size_t)r * (NT_NODES + 1) + i] = val;
  cursor[r * NT_NODES + i] = val;
}

__global__ __launch_bounds__(256) void csr_scatter(const int* __restrict__ edge_index,
                                                   int* __restrict__ cursor,
                                                   int* __restrict__ csr_src) {
  int idx = blockIdx.x * 256 + threadIdx.x;
  if (idx >= NRL * NE_EDGES) return;
  int r = idx / NE_EDGES, e = idx - r * NE_EDGES;
  int s = edge_index[(size_t)(r * 2 + 0) * NE_EDGES + e];
  int d = edge_index[(size_t)(r * 2 + 1) * NE_EDGES + e];
  int pos = atomicAdd(&cursor[r * NT_NODES + d], 1);
  csr_src[(size_t)r * NE_EDGES + pos] = s;
}

__global__ void csr_pad(int* __restrict__ pad) {
  if (threadIdx.x < 8) pad[threadIdx.x] = 0;
}

// ---------------------------------------------------- fused attention -------
// R9 layout (best measured): KV table [N][256] bf16, K in 0..127, V in
// 128..255. One wave per dst node; lane owns channels {2l,2l+1} (ushort2).
// 8-edge batches; transposed pair-reduce butterfly (7 shfl, 1 exp).
struct AttnRel {
  const int* csr_src; const int* off;
  const u16* q;        // bf16 Q of dst type [N,128]
  const u16* kv;       // bf16 K|V of src type [N,256]
  const float* Arel;   // [8][16][16]
  const float* Mrel;   // [8][16][16]
  const float* prel;   // [8]
  float* agg;          // output [N,128] (overwritten)
};
struct AttnBatch { AttnRel r[4]; };

__global__ __launch_bounds__(256) void attn_fused(AttnBatch ab) {
  const AttnRel rp = ab.r[blockIdx.y];
  const int wave = threadIdx.x >> 6;
  const int lane = threadIdx.x & 63;
  const int d = blockIdx.x * 4 + wave;
  if (d >= NT_NODES) return;
  const int h = lane >> 3;         // head 0..7
  const int el = lane & 7;         // pair index (channels 2el,2el+1)
  const int grp = h << 3;

  // ---- q' = (A_h @ q_h) * p_h/4 via shfl within 8-lane head groups ----
  ushort2 qu = ((const ushort2*)rp.q)[(size_t)d * 64 + lane];
  float q0 = bf2f(qu.x), q1 = bf2f(qu.y);
  const float* A = rp.Arel + (size_t)h * 256;
  float qp0 = 0.f, qp1 = 0.f;
  #pragma unroll
  for (int ee = 0; ee < 8; ee++) {
    float qa = __shfl(q0, grp + ee, 64);
    float qb = __shfl(q1, grp + ee, 64);
    qp0 += A[(2 * el) * 16 + 2 * ee] * qa + A[(2 * el) * 16 + 2 * ee + 1] * qb;
    qp1 += A[(2 * el + 1) * 16 + 2 * ee] * qa + A[(2 * el + 1) * 16 + 2 * ee + 1] * qb;
  }
  float sc = rp.prel[h] * 0.25f;
  qp0 *= sc; qp1 *= sc;

  const ushort2* KV = (const ushort2*)rp.kv;   // [N][128] ushort2 units
  const int* __restrict__ cs = rp.csr_src;
  int lo = rp.off[d], hi = rp.off[d + 1];
  lo = __builtin_amdgcn_readfirstlane(lo);
  hi = __builtin_amdgcn_readfirstlane(hi);
  float acc0 = 0.f, acc1 = 0.f, ssum = 0.f;
  for (int pos = lo; pos < hi; pos += 8) {
    int s0 = cs[pos + 0], s1 = cs[pos + 1], s2 = cs[pos + 2], s3 = cs[pos + 3];
    int s4 = cs[pos + 4], s5 = cs[pos + 5], s6 = cs[pos + 6], s7 = cs[pos + 7];
    ushort2 k0 = KV[(size_t)s0 * 128 + lane], k1 = KV[(size_t)s1 * 128 + lane];
    ushort2 k2 = KV[(size_t)s2 * 128 + lane], k3 = KV[(size_t)s3 * 128 + lane];
    ushort2 k4 = KV[(size_t)s4 * 128 + lane], k5 = KV[(size_t)s5 * 128 + lane];
    ushort2 k6 = KV[(size_t)s6 * 128 + lane], k7 = KV[(size_t)s7 * 128 + lane];
    ushort2 v0 = KV[(size_t)s0 * 128 + 64 + lane], v1 = KV[(size_t)s1 * 128 + 64 + lane];
    ushort2 v2 = KV[(size_t)s2 * 128 + 64 + lane], v3 = KV[(size_t)s3 * 128 + 64 + lane];
    ushort2 v4 = KV[(size_t)s4 * 128 + 64 + lane], v5 = KV[(size_t)s5 * 128 + 64 + lane];
    ushort2 v6 = KV[(size_t)s6 * 128 + 64 + lane], v7 = KV[(size_t)s7 * 128 + 64 + lane];
    float p0 = qp0 * bf2f(k0.x) + qp1 * bf2f(k0.y);
    float p1 = qp0 * bf2f(k1.x) + qp1 * bf2f(k1.y);
    float p2 = qp0 * bf2f(k2.x) + qp1 * bf2f(k2.y);
    float p3 = qp0 * bf2f(k3.x) + qp1 * bf2f(k3.y);
    float p4 = qp0 * bf2f(k4.x) + qp1 * bf2f(k4.y);
    float p5 = qp0 * bf2f(k5.x) + qp1 * bf2f(k5.y);
    float p6 = qp0 * bf2f(k6.x) + qp1 * bf2f(k6.y);
    float p7 = qp0 * bf2f(k7.x) + qp1 * bf2f(k7.y);
    // transposed pair-reduce butterfly: lane el ends with edge el's logit
    float s01 = (el & 1) ? p0 : p1, c01 = (el & 1) ? p1 : p0;
    float s23 = (el & 1) ? p2 : p3, c23 = (el & 1) ? p3 : p2;
    float s45 = (el & 1) ? p4 : p5, c45 = (el & 1) ? p5 : p4;
    float s67 = (el & 1) ? p6 : p7, c67 = (el & 1) ? p7 : p6;
    float r01 = c01 + __shfl_xor(s01, 1, 64);
    float r23 = c23 + __shfl_xor(s23, 1, 64);
    float r45 = c45 + __shfl_xor(s45, 1, 64);
    float r67 = c67 + __shfl_xor(s67, 1, 64);
    float sA = (el & 2) ? r01 : r23, cA = (el & 2) ? r23 : r01;
    float sB = (el & 2) ? r45 : r67, cB = (el & 2) ? r67 : r45;
    float rA = cA + __shfl_xor(sA, 2, 64);
    float rB = cB + __shfl_xor(sB, 2, 64);
    float sC = (el & 4) ? rA : rB, cC = (el & 4) ? rB : rA;
    float rF = cC + __shfl_xor(sC, 4, 64);
    int rem = hi - pos;   // scalar
    float e = (el < rem) ? __expf(rF) : 0.f;
    float e0 = __shfl(e, grp + 0, 64), e1 = __shfl(e, grp + 1, 64);
    float e2 = __shfl(e, grp + 2, 64), e3 = __shfl(e, grp + 3, 64);
    float e4 = __shfl(e, grp + 4, 64), e5 = __shfl(e, grp + 5, 64);
    float e6 = __shfl(e, grp + 6, 64), e7 = __shfl(e, grp + 7, 64);
    acc0 += e0 * bf2f(v0.x) + e1 * bf2f(v1.x) + e2 * bf2f(v2.x) + e3 * bf2f(v3.x)
          + e4 * bf2f(v4.x) + e5 * bf2f(v5.x) + e6 * bf2f(v6.x) + e7 * bf2f(v7.x);
    acc1 += e0 * bf2f(v0.y) + e1 * bf2f(v1.y) + e2 * bf2f(v2.y) + e3 * bf2f(v3.y)
          + e4 * bf2f(v4.y) + e5 * bf2f(v5.y) + e6 * bf2f(v6.y) + e7 * bf2f(v7.y);
    ssum += ((e0 + e1) + (e2 + e3)) + ((e4 + e5) + (e6 + e7));
  }
  float inv = 1.f / (ssum + 1e-16f);
  float S0 = acc0 * inv, S1 = acc1 * inv;

  // ---- apply M_rel: out_j = sum_d2 S[d2] * M[h][d2][j] ----
  const float* M = rp.Mrel + (size_t)h * 256;
  float o0 = 0.f, o1 = 0.f;
  #pragma unroll
  for (int dd = 0; dd < 8; dd++) {
    float sa = __shfl(S0, grp + dd, 64);
    float sb = __shfl(S1, grp + dd, 64);
    o0 += sa * M[(2 * dd) * 16 + 2 * el] + sb * M[(2 * dd + 1) * 16 + 2 * el];
    o1 += sa * M[(2 * dd) * 16 + 2 * el + 1] + sb * M[(2 * dd + 1) * 16 + 2 * el + 1];
  }
  float* ap = rp.agg + (size_t)d * FDIM + 2 * lane;
  *(float2*)ap = make_float2(o0, o1);
}

// ---------------------------------------------------------------- scatter ---
__global__ __launch_bounds__(256) void scatter_out(const float* h0, const float* h1,
                                                   const float* h2, const int* ntype,
                                                   float* out, int NN) {
  int idx = blockIdx.x * 256 + threadIdx.x;
  if (idx >= NN * 32) return;
  int i = idx >> 5, c4 = idx & 31;
  int t = ntype[i];
  const float* hp = (t == 0) ? h0 : ((t == 1) ? h1 : h2);
  int local = i - t * NT_NODES;
  ((float4*)out)[idx] = ((const float4*)hp)[(size_t)local * 32 + c4];
}

// ------------------------------------------------------------------- host ---
static const int ESRC[NRL] = {0, 0, 1, 0};
static const int EDST[NRL] = {0, 1, 0, 2};

extern "C" void kernel_launch(void* const* d_in, const int* in_sizes, int n_in,
                              void* d_out, int out_size, void* d_ws, size_t ws_size,
                              hipStream_t stream) {
  const float* x[3] = {(const float*)d_in[0], (const float*)d_in[1], (const float*)d_in[2]};
  const float* lin_w = (const float*)d_in[4];
  const float* lin_b = (const float*)d_in[5];
  const float* k_w   = (const float*)d_in[6];
  const float* k_b   = (const float*)d_in[7];
  const float* q_w   = (const float*)d_in[8];
  const float* q_b   = (const float*)d_in[9];
  const float* v_w   = (const float*)d_in[10];
  const float* v_b   = (const float*)d_in[11];
  const float* a_w   = (const float*)d_in[12];
  const float* a_b   = (const float*)d_in[13];
  const float* skip  = (const float*)d_in[14];
  const float* a_rel = (const float*)d_in[15];
  const float* m_rel = (const float*)d_in[16];
  const float* p_rel = (const float*)d_in[17];
  const int* edge_index = (const int*)d_in[18];
  const int* ntype   = (const int*)d_in[19];
  float* out = (float*)d_out;

  const size_t NF = (size_t)NT_NODES * FDIM;
  float* p = (float*)d_ws;
  auto alloc = [&](size_t n) { float* r = p; p += n; return r; };
  float* bufA = alloc(3 * NF);                    // h ping (bf16 in first half; f32 after final layer)
  float* bufB = alloc(3 * NF);                    // h pong / bf16 Q scratch
  float* agg  = alloc(3 * NF);                    // rels 0,1,3
  float* aggX = alloc(NF);                        // rel 2 (summed in out-GEMM)
  u16* kv0 = (u16*)alloc(NF);                     // K|V, src type 0 [N][256]
  u16* kv1 = (u16*)alloc(NF);                     // K|V, src type 1
  u16* wt  = (u16*)alloc(23 * FDIM * FDIM / 2);   // 23 bf16 W^T matrices
  int* counts  = (int*)(p);
  int* cursor  = counts + NRL * NT_NODES;
  int* offsets = cursor + NRL * NT_NODES;
  int* aux     = offsets + NRL * (NT_NODES + 1);
  int* auxe    = aux + NRL * SCAN_BLOCKS;
  int* csr_src = auxe + NRL * SCAN_BLOCKS;        // [4][E] + 8 slack

  const int gemm_gx = (NT_NODES + 63) / 64;   // 469

  // ---- weight prep: bf16 W^T (QKV 14, lin 3, a_w 6) ----
  {
    WtBatch wb{};
    for (int l = 0; l < NLY; l++) {
      for (int t = 0; t < 3; t++)
        wb.w[l * 7 + t] = q_w + (size_t)(l * NTY + t) * FDIM * FDIM;
      wb.w[l * 7 + 3] = k_w + (size_t)(l * NTY + 0) * FDIM * FDIM;
      wb.w[l * 7 + 4] = v_w + (size_t)(l * NTY + 0) * FDIM * FDIM;
      wb.w[l * 7 + 5] = k_w + (size_t)(l * NTY + 1) * FDIM * FDIM;
      wb.w[l * 7 + 6] = v_w + (size_t)(l * NTY + 1) * FDIM * FDIM;
    }
    for (int t = 0; t < 3; t++)
      wb.w[14 + t] = lin_w + (size_t)t * FDIM * FDIM;
    for (int l = 0; l < NLY; l++)
      for (int t = 0; t < 3; t++)
        wb.w[17 + l * 3 + t] = a_w + (size_t)(l * NTY + t) * FDIM * FDIM;
    wt_prep<<<dim3(23), 256, 0, stream>>>(wb, wt);
  }

  // ---- CSR build ----
  hipMemsetAsync(counts, 0, NRL * NT_NODES * sizeof(int), stream);
  csr_hist<<<dim3((NRL * NE_EDGES + 255) / 256), 256, 0, stream>>>(edge_index, counts);
  scan_block<<<dim3(SCAN_BLOCKS, NRL), 256, 0, stream>>>(counts, offsets, aux);
  scan_aux<<<dim3(NRL), 128, 0, stream>>>(aux, auxe, offsets);
  scan_add<<<dim3(SCAN_BLOCKS, NRL), 256, 0, stream>>>(auxe, offsets, cursor);
  csr_scatter<<<dim3((NRL * NE_EDGES + 255) / 256), 256, 0, stream>>>(edge_index, cursor, csr_src);
  csr_pad<<<dim3(1), 64, 0, stream>>>(csr_src + (size_t)NRL * NE_EDGES);

  // input projection: h[t] = relu(x_t @ lin_w[t] + lin_b[t])  (MFMA, bf16 out)
  {
    GemmBatchF gb{};
    for (int t = 0; t < 3; t++) {
      gb.t[t].A = x[t];
      gb.t[t].A2 = nullptr;
      gb.t[t].WT = wt + (size_t)(14 + t) * FDIM * FDIM;
      gb.t[t].bias = lin_b + (size_t)t * FDIM;
      gb.t[t].C = (float*)((u16*)bufA + (size_t)t * NF);
      gb.t[t].oldh = nullptr; gb.t[t].skipp = nullptr;
    }
    gemm_mfma_f<0, 0, 1, 1><<<dim3(gemm_gx, 1, 3), 256, 0, stream>>>(gb, NT_NODES);
  }

  float* cur = bufA;   // bf16 h
  float* alt = bufB;
  for (int l = 0; l < NLY; l++) {
    u16* qbf = (u16*)alt;
    const u16* hb = (const u16*)cur;

    // fused QKV: one A-stage per type, loop over weight matrices (MFMA bf16)
    {
      QkvBatch gb{};
      gb.t[0].A = hb;  gb.t[0].nout = 3;
      gb.t[0].o[0] = { wt + (size_t)(l * 7 + 0) * FDIM * FDIM, q_b + (size_t)(l * NTY + 0) * FDIM, qbf,            FDIM };
      gb.t[0].o[1] = { wt + (size_t)(l * 7 + 3) * FDIM * FDIM, k_b + (size_t)(l * NTY + 0) * FDIM, kv0,            256 };
      gb.t[0].o[2] = { wt + (size_t)(l * 7 + 4) * FDIM * FDIM, v_b + (size_t)(l * NTY + 0) * FDIM, kv0 + 128,      256 };
      gb.t[1].A = hb + NF;  gb.t[1].nout = 3;
      gb.t[1].o[0] = { wt + (size_t)(l * 7 + 1) * FDIM * FDIM, q_b + (size_t)(l * NTY + 1) * FDIM, qbf + NF,       FDIM };
      gb.t[1].o[1] = { wt + (size_t)(l * 7 + 5) * FDIM * FDIM, k_b + (size_t)(l * NTY + 1) * FDIM, kv1,            256 };
      gb.t[1].o[2] = { wt + (size_t)(l * 7 + 6) * FDIM * FDIM, v_b + (size_t)(l * NTY + 1) * FDIM, kv1 + 128,      256 };
      gb.t[2].A = hb + 2 * NF;  gb.t[2].nout = 1;
      gb.t[2].o[0] = { wt + (size_t)(l * 7 + 2) * FDIM * FDIM, q_b + (size_t)(l * NTY + 2) * FDIM, qbf + 2 * NF,   FDIM };
      gemm_qkv<<<dim3(gemm_gx, 1, 3), 256, 0, stream>>>(gb, NT_NODES);
    }

    // attention: all 4 relations, one launch
    {
      AttnBatch ab{};
      for (int r = 0; r < NRL; r++) {
        int dt = EDST[r];
        ab.r[r].csr_src = csr_src + (size_t)r * NE_EDGES;
        ab.r[r].off  = offsets + (size_t)r * (NT_NODES + 1);
        ab.r[r].q    = qbf + (size_t)dt * NF;
        ab.r[r].kv   = (ESRC[r] == 0) ? kv0 : kv1;
        ab.r[r].Arel = a_rel + (size_t)(l * NRL + r) * NH * HD * HD;
        ab.r[r].Mrel = m_rel + (size_t)(l * NRL + r) * NH * HD * HD;
        ab.r[r].prel = p_rel + (size_t)(l * NRL + r) * NH;
        ab.r[r].agg  = (r == 2) ? aggX : (agg + (size_t)dt * NF);
      }
      attn_fused<<<dim3((NT_NODES + 3) / 4, NRL), 256, 0, stream>>>(ab);
    }

    // out: h_new[t] = a_s*(gelu(agg[t] [+aggX]) @ a_w + a_b) + (1-a_s)*h[t]
    // layer 0 -> bf16 h; final layer -> f32 h (scatter needs full precision)
    {
      GemmBatchF gb{};
      for (int t = 0; t < 3; t++) {
        gb.t[t].A = agg + (size_t)t * NF;
        gb.t[t].A2 = (t == 0) ? aggX : nullptr;
        gb.t[t].WT = wt + (size_t)(17 + l * 3 + t) * FDIM * FDIM;
        gb.t[t].bias = a_b + (size_t)(l * NTY + t) * FDIM;
        gb.t[t].oldh = hb + (size_t)t * NF;
        gb.t[t].skipp = skip + (size_t)(l * NTY + t);
        if (l == 0) gb.t[t].C = (float*)((u16*)alt + (size_t)t * NF);
        else        gb.t[t].C = alt + (size_t)t * NF;
      }
      if (l == 0) gemm_mfma_f<1, 1, 0, 1><<<dim3(gemm_gx, 1, 3), 256, 0, stream>>>(gb, NT_NODES);
      else        gemm_mfma_f<1, 1, 0, 0><<<dim3(gemm_gx, 1, 3), 256, 0, stream>>>(gb, NT_NODES);
    }
    float* tmp = cur; cur = alt; alt = tmp;
  }

  const int NN = 3 * NT_NODES;
  scatter_out<<<dim3((NN * 32 + 255) / 256), 256, 0, stream>>>(
      cur, cur + NF, cur + 2 * NF, ntype, out, NN);
}